// Round 14
// baseline (576.457 us; speedup 1.0000x reference)
//
#include <hip/hip_runtime.h>
#include <hip/hip_bf16.h>

#define D 128
#define EPS 1e-5f
#define SLOTS 128
#define NP 8
#define BINCAP 384

typedef __attribute__((ext_vector_type(8))) short short8v;
typedef __attribute__((ext_vector_type(4))) float floatx4;
typedef __attribute__((ext_vector_type(4))) int int4v;

__device__ __forceinline__ unsigned short f2bf(float f) {
    union { float f; unsigned u; } v; v.f = f;
    unsigned r = (v.u + 0x7FFF + ((v.u >> 16) & 1)) >> 16;
    return (unsigned short)r;
}
__device__ __forceinline__ float bf2f(unsigned short h) {
    union { unsigned u; float f; } v; v.u = ((unsigned)h) << 16;
    return v.f;
}

// ---------------- phase 1: block-level LDS-binned scatter (barrier-synced) ----------
// entry = src | (d - lo(p)) << 16 (both < 65536). Bins are BLOCK-level; adds and
// flushes are separated by __syncthreads(); wave w owns bins 2w,2w+1 during flush.

__global__ __launch_bounds__(256) void scatter_kernel(const int* __restrict__ src,
                                                      const int* __restrict__ dst,
                                                      int* __restrict__ pcur,
                                                      unsigned* __restrict__ st,
                                                      int E, int N) {
    __shared__ unsigned bbuf[NP][BINCAP];
    __shared__ int bcnt[NP];
    int tid  = threadIdx.x;
    int lane = tid & 63;
    int w    = tid >> 6;
    if (tid < NP) bcnt[tid] = 0;
    __syncthreads();

    int stride = gridDim.x * 256;
    int rounds = (E + stride - 1) / stride;
    int e0 = blockIdx.x * 256 + tid;

    for (int r = 0; r < rounds; ++r) {
        int e = e0 + r * stride;
        if (e < E) {
            int d = dst[e];
            int s = src[e];
            int p = (int)((unsigned)(d * NP) / (unsigned)N);
            int lo = (p * N) / NP;
            unsigned pk = (unsigned)(s & 0xFFFF) | ((unsigned)(d - lo) << 16);
            int pos = atomicAdd(&bcnt[p], 1);   // < BINCAP: carry(<64) + 256
            bbuf[p][pos] = pk;
        }
        __syncthreads();
        // flush multiples of 64; wave w owns bins 2w, 2w+1
        #pragma unroll
        for (int qq = 0; qq < 2; ++qq) {
            int q = w * 2 + qq;
            int c = bcnt[q];
            int f = c & ~63;
            if (f > 0) {
                int base = 0;
                if (lane == 0) base = atomicAdd(&pcur[q], f);
                base = __shfl(base, 0);
                for (int k = lane; k < f; k += 64)
                    st[base + k] = bbuf[q][k];
                int rem = c - f;                     // < 64 <= f: move is disjoint
                unsigned mv = (lane < rem) ? bbuf[q][f + lane] : 0u;
                if (lane < rem) bbuf[q][lane] = mv;
                if (lane == 0) bcnt[q] = rem;
            }
        }
        __syncthreads();
    }
    // drain (each bin < 64)
    #pragma unroll
    for (int qq = 0; qq < 2; ++qq) {
        int q = w * 2 + qq;
        int c = bcnt[q];
        if (c > 0) {
            int base = 0;
            if (lane == 0) base = atomicAdd(&pcur[q], c);
            base = __shfl(base, 0);
            if (lane < c) st[base + lane] = bbuf[q][lane];
        }
    }
}

// ---------------- phase 2: merged count+fill from partition-contiguous staging ----

__global__ __launch_bounds__(256) void build2_kernel(const unsigned* __restrict__ st,
                                                     const int* __restrict__ pcur,
                                                     int* __restrict__ cnt,
                                                     unsigned short* __restrict__ col,
                                                     int N, int cap) {
    int p  = blockIdx.x & 7;
    int lo = (p * N) / NP;
    int pb = p * cap;
    int pe = pcur[p];
    int blk = blockIdx.x >> 3;
    int stride = (gridDim.x >> 3) * 256;
    for (int e = pb + blk * 256 + (int)threadIdx.x; e < pe; e += stride) {
        unsigned v = __builtin_nontemporal_load(st + e);
        int d = lo + (int)(v >> 16);
        int pos = atomicAdd(&cnt[d], 1);
        if (pos < SLOTS) col[(size_t)d * SLOTS + pos] = (unsigned short)(v & 0xFFFF);
    }
}

// init: zero dummy msc row (both 64-col slices) + init pcur
__global__ void init_kernel(unsigned short* __restrict__ msc, int n,
                            int* __restrict__ pcur, int cap) {
    int t = threadIdx.x;   // 128 threads: slice t>>6, col t&63
    msc[((size_t)(t >> 6) * (n + 1) + n) * 64 + (t & 63)] = 0;
    if (t < NP) pcur[t] = t * cap;
}

// fused pad (to x8 with dummy index N) + dinv
__global__ __launch_bounds__(256) void paddinv_kernel(const int* __restrict__ cnt,
                                                      unsigned short* __restrict__ col,
                                                      float* __restrict__ dinv,
                                                      int n, int N) {
    int i = blockIdx.x * 256 + threadIdx.x;
    if (i >= n) return;
    int deg0 = cnt[i];
    dinv[i] = rsqrtf((float)(deg0 + 1));
    int deg = (deg0 < SLOTS) ? deg0 : SLOTS;
    int end = (deg + 7) & ~7; end = (end < SLOTS) ? end : SLOTS;
    unsigned short* c = col + (size_t)i * SLOTS;
    for (int s = deg; s < end; ++s) c[s] = (unsigned short)N;
}

// ---------------- W precompute: transpose + bf16 hi/lo split ----------------

__global__ void wprep_kernel(const float* __restrict__ W1, const float* __restrict__ W2,
                             const float* __restrict__ W3, unsigned short* __restrict__ wt) {
    int gid = blockIdx.x * 256 + threadIdx.x;   // 0 .. 3*16384
    int z = gid >> 14;
    int r = gid & 16383;
    int c = r >> 7, k = r & 127;
    const float* W = (z == 0) ? W1 : ((z == 1) ? W2 : W3);
    float v = W[k * D + c];
    unsigned short hi = f2bf(v);
    unsigned short lo = f2bf(v - bf2f(hi));
    wt[(size_t)(z * 2 + 0) * 16384 + r] = hi;
    wt[(size_t)(z * 2 + 1) * 16384 + r] = lo;
}

// ---------------- MFMA GEMM -> sliced msc: msc[sl(2)][row][64], pre-scaled by dinv ----

__device__ __forceinline__ int sw_sidx(int row, int k) {   // short index, XOR-swizzled
    int byte = row * 256 + k * 2;
    byte ^= (row & 7) << 4;
    return byte >> 1;
}

template <int AMODE>
__global__ __launch_bounds__(256, 1) void gemm_kernel(const float* __restrict__ A,
                                                      const unsigned short* __restrict__ Agh,
                                                      const unsigned short* __restrict__ Agl,
                                                      const unsigned short* __restrict__ wt_hi,
                                                      const unsigned short* __restrict__ wt_lo,
                                                      const float* __restrict__ dinv,
                                                      unsigned short* __restrict__ msc, int n) {
    __shared__ short lds[4 * 16384];
    short* Ah = lds;
    short* Al = lds + 16384;
    short* Wh = lds + 32768;
    short* Wl = lds + 49152;

    const int t = threadIdx.x;
    const int rb = blockIdx.x * 128;

    #pragma unroll
    for (int p = 0; p < 8; ++p) {
        int chunk = p * 256 + t;
        int c = chunk >> 4, k0 = (chunk & 15) << 3;
        int si = sw_sidx(c, k0);
        *(short8v*)&Wh[si] = *(const short8v*)&wt_hi[c * D + k0];
        *(short8v*)&Wl[si] = *(const short8v*)&wt_lo[c * D + k0];
    }
    #pragma unroll
    for (int p = 0; p < 8; ++p) {
        int chunk = p * 256 + t;
        int r = chunk >> 4, k0 = (chunk & 15) << 3;
        int row = rb + r;
        int rowc = (row < n) ? row : (n - 1);
        int si = sw_sidx(r, k0);
        if (AMODE == 0) {
            float4 f0 = *(const float4*)&A[(size_t)rowc * D + k0];
            float4 f1 = *(const float4*)&A[(size_t)rowc * D + k0 + 4];
            float fv[8] = {f0.x, f0.y, f0.z, f0.w, f1.x, f1.y, f1.z, f1.w};
            short8v hi, lo;
            #pragma unroll
            for (int j = 0; j < 8; ++j) {
                unsigned short h = f2bf(fv[j]);
                hi[j] = (short)h;
                lo[j] = (short)f2bf(fv[j] - bf2f(h));
            }
            *(short8v*)&Ah[si] = hi;
            *(short8v*)&Al[si] = lo;
        } else {
            *(short8v*)&Ah[si] = *(const short8v*)&Agh[(size_t)rowc * D + k0];
            *(short8v*)&Al[si] = *(const short8v*)&Agl[(size_t)rowc * D + k0];
        }
    }
    __syncthreads();

    const int lane = t & 63;
    const int wid  = t >> 6;
    const int wr = (wid & 1) * 64;
    const int wc = (wid >> 1) * 64;

    floatx4 acc[4][4];
    #pragma unroll
    for (int m = 0; m < 4; ++m)
        #pragma unroll
        for (int nn = 0; nn < 4; ++nn)
            acc[m][nn] = (floatx4){0.f, 0.f, 0.f, 0.f};

    #pragma unroll
    for (int ks = 0; ks < 4; ++ks) {
        const int kk = ks * 32 + (lane >> 4) * 8;
        short8v ah[4], al[4], bh[4], bl[4];
        #pragma unroll
        for (int m = 0; m < 4; ++m) {
            int si = sw_sidx(wr + m * 16 + (lane & 15), kk);
            ah[m] = *(const short8v*)&Ah[si];
            al[m] = *(const short8v*)&Al[si];
        }
        #pragma unroll
        for (int nn = 0; nn < 4; ++nn) {
            int si = sw_sidx(wc + nn * 16 + (lane & 15), kk);
            bh[nn] = *(const short8v*)&Wh[si];
            bl[nn] = *(const short8v*)&Wl[si];
        }
        #pragma unroll
        for (int m = 0; m < 4; ++m)
            #pragma unroll
            for (int nn = 0; nn < 4; ++nn) {
                acc[m][nn] = __builtin_amdgcn_mfma_f32_16x16x32_bf16(ah[m], bh[nn], acc[m][nn], 0, 0, 0);
                acc[m][nn] = __builtin_amdgcn_mfma_f32_16x16x32_bf16(al[m], bh[nn], acc[m][nn], 0, 0, 0);
                acc[m][nn] = __builtin_amdgcn_mfma_f32_16x16x32_bf16(ah[m], bl[nn], acc[m][nn], 0, 0, 0);
            }
    }

    // epilogue: msc[(colr>>6)][(row)][colr&63]
    #pragma unroll
    for (int m = 0; m < 4; ++m) {
        #pragma unroll
        for (int j = 0; j < 4; ++j) {
            int row = rb + wr + m * 16 + (lane >> 4) * 4 + j;
            if (row < n) {
                float dv = dinv[row];
                #pragma unroll
                for (int nn = 0; nn < 4; ++nn) {
                    int colr = wc + nn * 16 + (lane & 15);
                    msc[((size_t)(colr >> 6) * (n + 1) + row) * 64 + (colr & 63)] =
                        f2bf(dv * acc[m][nn][j]);
                }
            }
        }
    }
}

// ---------------- feature-sliced aggregation, 2 slices x 64 cols (unchanged) --------

template <bool WF32>
__global__ __launch_bounds__(256) void agg_sl(const unsigned short* __restrict__ msc,
                                              const int* __restrict__ cnt,
                                              const unsigned short* __restrict__ col,
                                              const float* __restrict__ dinv,
                                              const float* __restrict__ bias,
                                              float* __restrict__ out,
                                              unsigned short* __restrict__ asl, int n) {
    int lane = threadIdx.x & 63;
    int g    = lane >> 3;    // group 0..7 -> node
    int l8   = lane & 7;     // 8-col chunk within 64-col slice
    int wid  = threadIdx.x >> 6;
    int p    = blockIdx.x & 1;
    int bi   = blockIdx.x >> 1;
    int nblk = gridDim.x >> 1;

    const unsigned short* msl = msc + (size_t)p * (n + 1) * 64;
    int cbase = p * 64 + l8 * 8;

    for (int i = bi * 32 + wid * 8 + g; i < n; i += nblk * 32) {
        float a0, a1, a2, a3, a4, a5, a6, a7;
        {   // self loop init
            short8v v = *(const short8v*)&msl[(size_t)i * 64 + l8 * 8];
            a0 = bf2f((unsigned short)v[0]); a1 = bf2f((unsigned short)v[1]);
            a2 = bf2f((unsigned short)v[2]); a3 = bf2f((unsigned short)v[3]);
            a4 = bf2f((unsigned short)v[4]); a5 = bf2f((unsigned short)v[5]);
            a6 = bf2f((unsigned short)v[6]); a7 = bf2f((unsigned short)v[7]);
        }
        int deg = cnt[i]; deg = (deg < SLOTS) ? deg : SLOTS;
        int degR = (deg + 7) & ~7; degR = (degR < SLOTS) ? degR : SLOTS;
        const unsigned short* crow = col + (size_t)i * SLOTS;
        for (int base = 0; base < degR; base += 8) {
            short8v ci = *(const short8v*)&crow[base];
            #pragma unroll
            for (int u = 0; u < 8; ++u) {
                unsigned j = (unsigned short)ci[u];
                short8v v = *(const short8v*)&msl[(size_t)j * 64 + l8 * 8];
                a0 += bf2f((unsigned short)v[0]); a1 += bf2f((unsigned short)v[1]);
                a2 += bf2f((unsigned short)v[2]); a3 += bf2f((unsigned short)v[3]);
                a4 += bf2f((unsigned short)v[4]); a5 += bf2f((unsigned short)v[5]);
                a6 += bf2f((unsigned short)v[6]); a7 += bf2f((unsigned short)v[7]);
            }
        }
        if (WF32) {
            float di = dinv[i];
            float4 b0 = *(const float4*)&bias[cbase];
            float4 b1 = *(const float4*)&bias[cbase + 4];
            floatx4 r0 = {fmaf(di, a0, b0.x), fmaf(di, a1, b0.y),
                          fmaf(di, a2, b0.z), fmaf(di, a3, b0.w)};
            floatx4 r1 = {fmaf(di, a4, b1.x), fmaf(di, a5, b1.y),
                          fmaf(di, a6, b1.z), fmaf(di, a7, b1.w)};
            floatx4* o4 = (floatx4*)&out[(size_t)i * D + cbase];
            o4[0] = r0;
            o4[1] = r1;
        } else {
            short8v r;
            r[0] = (short)f2bf(a0); r[1] = (short)f2bf(a1);
            r[2] = (short)f2bf(a2); r[3] = (short)f2bf(a3);
            r[4] = (short)f2bf(a4); r[5] = (short)f2bf(a5);
            r[6] = (short)f2bf(a6); r[7] = (short)f2bf(a7);
            *(short8v*)&asl[((size_t)p * n + i) * 64 + l8 * 8] = r;
        }
    }
}

// ---------------- LN pass (unchanged) ----------------

template <bool WF32OUT>
__global__ __launch_bounds__(256) void ln_kernel(const unsigned short* __restrict__ asl,
                                                 const float* __restrict__ dinv,
                                                 const float* __restrict__ bias,
                                                 const float* __restrict__ gamma,
                                                 const float* __restrict__ beta,
                                                 float* __restrict__ out,
                                                 unsigned short* __restrict__ oh,
                                                 unsigned short* __restrict__ ol, int n) {
    int lane = threadIdx.x & 63;
    int g    = lane >> 4;
    int l16  = lane & 15;
    int wid  = threadIdx.x >> 6;
    int i = blockIdx.x * 16 + wid * 4 + g;
    if (i >= n) return;

    short8v v = *(const short8v*)&asl[((size_t)(l16 >> 3) * n + i) * 64 + (l16 & 7) * 8];
    float di = dinv[i];
    float4 b0 = ((const float4*)bias)[l16 * 2];
    float4 b1 = ((const float4*)bias)[l16 * 2 + 1];
    float a[8];
    a[0] = fmaf(di, bf2f((unsigned short)v[0]), b0.x);
    a[1] = fmaf(di, bf2f((unsigned short)v[1]), b0.y);
    a[2] = fmaf(di, bf2f((unsigned short)v[2]), b0.z);
    a[3] = fmaf(di, bf2f((unsigned short)v[3]), b0.w);
    a[4] = fmaf(di, bf2f((unsigned short)v[4]), b1.x);
    a[5] = fmaf(di, bf2f((unsigned short)v[5]), b1.y);
    a[6] = fmaf(di, bf2f((unsigned short)v[6]), b1.z);
    a[7] = fmaf(di, bf2f((unsigned short)v[7]), b1.w);

    float s = 0.f, ss = 0.f;
    #pragma unroll
    for (int j = 0; j < 8; ++j) { s += a[j]; ss += a[j] * a[j]; }
    #pragma unroll
    for (int off = 1; off < 16; off <<= 1) {
        s  += __shfl_xor(s, off, 64);
        ss += __shfl_xor(ss, off, 64);
    }
    float mu   = s * (1.0f / D);
    float var  = ss * (1.0f / D) - mu * mu;
    float rstd = rsqrtf(var + EPS);

    float4 g0 = ((const float4*)gamma)[l16 * 2];
    float4 g1 = ((const float4*)gamma)[l16 * 2 + 1];
    float4 e0 = ((const float4*)beta)[l16 * 2];
    float4 e1 = ((const float4*)beta)[l16 * 2 + 1];
    float gv[8] = {g0.x, g0.y, g0.z, g0.w, g1.x, g1.y, g1.z, g1.w};
    float ev[8] = {e0.x, e0.y, e0.z, e0.w, e1.x, e1.y, e1.z, e1.w};
    #pragma unroll
    for (int j = 0; j < 8; ++j)
        a[j] = fmaxf((a[j] - mu) * rstd * gv[j] + ev[j], 0.f);

    if (WF32OUT) {
        floatx4 r0 = {a[0], a[1], a[2], a[3]};
        floatx4 r1 = {a[4], a[5], a[6], a[7]};
        floatx4* o4 = (floatx4*)out;
        o4[(size_t)i * 32 + l16 * 2]     = r0;
        o4[(size_t)i * 32 + l16 * 2 + 1] = r1;
    }
    short8v h, l;
    #pragma unroll
    for (int j = 0; j < 8; ++j) {
        unsigned short hb = f2bf(a[j]);
        h[j] = (short)hb;
        l[j] = (short)f2bf(a[j] - bf2f(hb));
    }
    *(short8v*)&oh[(size_t)i * D + l16 * 8] = h;
    *(short8v*)&ol[(size_t)i * D + l16 * 8] = l;
}

// ---------------- launch ----------------

static inline size_t align_up(size_t v, size_t a) { return (v + a - 1) & ~(a - 1); }

extern "C" void kernel_launch(void* const* d_in, const int* in_sizes, int n_in,
                              void* d_out, int out_size, void* d_ws, size_t ws_size,
                              hipStream_t stream) {
    const float* x  = (const float*)d_in[0];
    const int*   ei = (const int*)d_in[1];
    const float* W1 = (const float*)d_in[2];
    const float* b1 = (const float*)d_in[3];
    const float* W2 = (const float*)d_in[4];
    const float* b2 = (const float*)d_in[5];
    const float* W3 = (const float*)d_in[6];
    const float* b3 = (const float*)d_in[7];
    const float* g1  = (const float*)d_in[8];
    const float* be1 = (const float*)d_in[9];
    const float* g2  = (const float*)d_in[10];
    const float* be2 = (const float*)d_in[11];

    int N = in_sizes[0] / D;
    int E = in_sizes[1] / 2;
    const int* srcv = ei;
    const int* dstv = ei + E;

    float* out   = (float*)d_out;
    float* h2out = out;
    float* h3out = out + (size_t)N * D;

    int cap = ((E / NP + 16384 + 63) / 64) * 64;   // per-partition staging capacity

    char* w = (char*)d_ws;
    int* cnt = (int*)w;      w += align_up((size_t)N * 4, 256);
    float* dinv = (float*)w; w += align_up((size_t)N * 4, 256);
    int* pcur = (int*)w;     w += align_up(NP * 4, 256);
    unsigned short* wt = (unsigned short*)w;   w += align_up((size_t)3 * 2 * 16384 * 2, 256);
    unsigned short* colA = (unsigned short*)w; w += align_up((size_t)N * SLOTS * 2, 256);
    unsigned short* msc = (unsigned short*)w;  w += align_up((size_t)(N + 1) * D * 2, 256);
    unsigned short* asl = (unsigned short*)w;  w += align_up((size_t)N * D * 2, 256);
    unsigned short* hh = (unsigned short*)w;   w += align_up((size_t)N * D * 2, 256);
    unsigned short* hl = (unsigned short*)w;   w += align_up((size_t)N * D * 2, 256);

    // staging overlays asl (dead until agg1): NP*cap*4 bytes ~ 6.9MB < 12.8MB
    unsigned* st = (unsigned*)asl;

    wprep_kernel<<<192, 256, 0, stream>>>(W1, W2, W3, wt);
    hipMemsetAsync(cnt, 0, (size_t)N * sizeof(int), stream);
    init_kernel<<<1, 128, 0, stream>>>(msc, N, pcur, cap);
    scatter_kernel<<<256, 256, 0, stream>>>(srcv, dstv, pcur, st, E, N);
    build2_kernel<<<2048, 256, 0, stream>>>(st, pcur, cnt, colA, N, cap);
    paddinv_kernel<<<(N + 255) / 256, 256, 0, stream>>>(cnt, colA, dinv, N, N);

    int gemmGrid = (N + 127) / 128;
    int aggGrid  = 2048;
    int lnGrid   = (N + 15) / 16;

    const unsigned short* wt1h = wt + 0 * 16384;
    const unsigned short* wt1l = wt + 1 * 16384;
    const unsigned short* wt2h = wt + 2 * 16384;
    const unsigned short* wt2l = wt + 3 * 16384;
    const unsigned short* wt3h = wt + 4 * 16384;
    const unsigned short* wt3l = wt + 5 * 16384;

    // layer 1
    gemm_kernel<0><<<gemmGrid, 256, 0, stream>>>(x, nullptr, nullptr, wt1h, wt1l, dinv, msc, N);
    agg_sl<false><<<aggGrid, 256, 0, stream>>>(msc, cnt, colA, dinv, b1, nullptr, asl, N);
    ln_kernel<false><<<lnGrid, 256, 0, stream>>>(asl, dinv, b1, g1, be1, nullptr, hh, hl, N);
    // layer 2
    gemm_kernel<1><<<gemmGrid, 256, 0, stream>>>(nullptr, hh, hl, wt2h, wt2l, dinv, msc, N);
    agg_sl<false><<<aggGrid, 256, 0, stream>>>(msc, cnt, colA, dinv, b2, nullptr, asl, N);
    ln_kernel<true><<<lnGrid, 256, 0, stream>>>(asl, dinv, b2, g2, be2, h2out, hh, hl, N);
    // layer 3
    gemm_kernel<1><<<gemmGrid, 256, 0, stream>>>(nullptr, hh, hl, wt3h, wt3l, dinv, msc, N);
    agg_sl<true><<<aggGrid, 256, 0, stream>>>(msc, cnt, colA, dinv, b3, h3out, nullptr, N);
}

// Round 15
// 284.394 us; speedup vs baseline: 2.0270x; 2.0270x over previous
//
#include <hip/hip_runtime.h>
#include <hip/hip_bf16.h>

#define D 128
#define EPS 1e-5f
#define SLOTS 128

typedef __attribute__((ext_vector_type(8))) short short8v;
typedef __attribute__((ext_vector_type(4))) float floatx4;
typedef __attribute__((ext_vector_type(4))) int int4v;

__device__ __forceinline__ unsigned short f2bf(float f) {
    union { float f; unsigned u; } v; v.f = f;
    unsigned r = (v.u + 0x7FFF + ((v.u >> 16) & 1)) >> 16;
    return (unsigned short)r;
}
__device__ __forceinline__ float bf2f(unsigned short h) {
    union { unsigned u; float f; } v; v.u = ((unsigned)h) << 16;
    return v.f;
}

// ---------------- merged CSR build: one pass, fixed-slot table, NP=4 ----------------
// col[d*SLOTS + rank] = src (ushort). 4 passes (blockIdx&3); partition k's blocks
// land on XCDs {k, k+4}; col slice 3.2MB + cnt fit in L2.

__global__ __launch_bounds__(256) void build_kernel(const int* __restrict__ src,
                                                    const int* __restrict__ dst,
                                                    int* __restrict__ cnt,
                                                    unsigned short* __restrict__ col,
                                                    int E, int N) {
    int p   = blockIdx.x & 3;
    int lo  = (int)((long long)p * N / 4);
    int hi  = (int)((long long)(p + 1) * N / 4);
    int blk = blockIdx.x >> 2;
    int stride = (gridDim.x >> 2) * 256;
    int E4 = E >> 2;
    const int4v* dst4 = (const int4v*)dst;
    const int4v* src4 = (const int4v*)src;
    for (int e = blk * 256 + (int)threadIdx.x; e < E4; e += stride) {
        int4v d = __builtin_nontemporal_load(dst4 + e);
        int4v s = __builtin_nontemporal_load(src4 + e);
        #pragma unroll
        for (int u = 0; u < 4; ++u) {
            int dd = d[u];
            if (dd >= lo && dd < hi) {
                int pos = atomicAdd(&cnt[dd], 1);
                if (pos < SLOTS) col[(size_t)dd * SLOTS + pos] = (unsigned short)s[u];
            }
        }
    }
    if (p == 0 && blk == 0 && threadIdx.x < (unsigned)(E & 3)) {
        int e = E4 * 4 + (int)threadIdx.x;
        int d = dst[e];
        int pos = atomicAdd(&cnt[d], 1);
        if (pos < SLOTS) col[(size_t)d * SLOTS + pos] = (unsigned short)src[e];
    }
}

// fused pad (to x8 with dummy index N) + dinv
__global__ __launch_bounds__(256) void paddinv_kernel(const int* __restrict__ cnt,
                                                      unsigned short* __restrict__ col,
                                                      float* __restrict__ dinv,
                                                      int n, int N) {
    int i = blockIdx.x * 256 + threadIdx.x;
    if (i >= n) return;
    int deg0 = cnt[i];
    dinv[i] = rsqrtf((float)(deg0 + 1));
    int deg = (deg0 < SLOTS) ? deg0 : SLOTS;
    int end = (deg + 7) & ~7; end = (end < SLOTS) ? end : SLOTS;
    unsigned short* c = col + (size_t)i * SLOTS;
    for (int s = deg; s < end; ++s) c[s] = (unsigned short)N;
}

// zero the dummy row N in both 64-col slices of msc
__global__ void zdum_kernel(unsigned short* __restrict__ msc, int n) {
    int t = threadIdx.x;   // 128 threads: slice t>>6, col t&63
    msc[((size_t)(t >> 6) * (n + 1) + n) * 64 + (t & 63)] = 0;
}

// ---------------- W precompute: transpose + bf16 hi/lo split ----------------

__global__ void wprep_kernel(const float* __restrict__ W1, const float* __restrict__ W2,
                             const float* __restrict__ W3, unsigned short* __restrict__ wt) {
    int gid = blockIdx.x * 256 + threadIdx.x;   // 0 .. 3*16384
    int z = gid >> 14;
    int r = gid & 16383;
    int c = r >> 7, k = r & 127;
    const float* W = (z == 0) ? W1 : ((z == 1) ? W2 : W3);
    float v = W[k * D + c];
    unsigned short hi = f2bf(v);
    unsigned short lo = f2bf(v - bf2f(hi));
    wt[(size_t)(z * 2 + 0) * 16384 + r] = hi;
    wt[(size_t)(z * 2 + 1) * 16384 + r] = lo;
}

// ---------------- MFMA GEMM -> sliced msc: msc[sl(2)][row][64], pre-scaled by dinv ----

__device__ __forceinline__ int sw_sidx(int row, int k) {   // short index, XOR-swizzled
    int byte = row * 256 + k * 2;
    byte ^= (row & 7) << 4;
    return byte >> 1;
}

template <int AMODE>
__global__ __launch_bounds__(256, 1) void gemm_kernel(const float* __restrict__ A,
                                                      const unsigned short* __restrict__ Agh,
                                                      const unsigned short* __restrict__ Agl,
                                                      const unsigned short* __restrict__ wt_hi,
                                                      const unsigned short* __restrict__ wt_lo,
                                                      const float* __restrict__ dinv,
                                                      unsigned short* __restrict__ msc, int n) {
    __shared__ short lds[4 * 16384];
    short* Ah = lds;
    short* Al = lds + 16384;
    short* Wh = lds + 32768;
    short* Wl = lds + 49152;

    const int t = threadIdx.x;
    const int rb = blockIdx.x * 128;

    #pragma unroll
    for (int p = 0; p < 8; ++p) {
        int chunk = p * 256 + t;
        int c = chunk >> 4, k0 = (chunk & 15) << 3;
        int si = sw_sidx(c, k0);
        *(short8v*)&Wh[si] = *(const short8v*)&wt_hi[c * D + k0];
        *(short8v*)&Wl[si] = *(const short8v*)&wt_lo[c * D + k0];
    }
    #pragma unroll
    for (int p = 0; p < 8; ++p) {
        int chunk = p * 256 + t;
        int r = chunk >> 4, k0 = (chunk & 15) << 3;
        int row = rb + r;
        int rowc = (row < n) ? row : (n - 1);
        int si = sw_sidx(r, k0);
        if (AMODE == 0) {
            float4 f0 = *(const float4*)&A[(size_t)rowc * D + k0];
            float4 f1 = *(const float4*)&A[(size_t)rowc * D + k0 + 4];
            float fv[8] = {f0.x, f0.y, f0.z, f0.w, f1.x, f1.y, f1.z, f1.w};
            short8v hi, lo;
            #pragma unroll
            for (int j = 0; j < 8; ++j) {
                unsigned short h = f2bf(fv[j]);
                hi[j] = (short)h;
                lo[j] = (short)f2bf(fv[j] - bf2f(h));
            }
            *(short8v*)&Ah[si] = hi;
            *(short8v*)&Al[si] = lo;
        } else {
            *(short8v*)&Ah[si] = *(const short8v*)&Agh[(size_t)rowc * D + k0];
            *(short8v*)&Al[si] = *(const short8v*)&Agl[(size_t)rowc * D + k0];
        }
    }
    __syncthreads();

    const int lane = t & 63;
    const int wid  = t >> 6;
    const int wr = (wid & 1) * 64;
    const int wc = (wid >> 1) * 64;

    floatx4 acc[4][4];
    #pragma unroll
    for (int m = 0; m < 4; ++m)
        #pragma unroll
        for (int nn = 0; nn < 4; ++nn)
            acc[m][nn] = (floatx4){0.f, 0.f, 0.f, 0.f};

    #pragma unroll
    for (int ks = 0; ks < 4; ++ks) {
        const int kk = ks * 32 + (lane >> 4) * 8;
        short8v ah[4], al[4], bh[4], bl[4];
        #pragma unroll
        for (int m = 0; m < 4; ++m) {
            int si = sw_sidx(wr + m * 16 + (lane & 15), kk);
            ah[m] = *(const short8v*)&Ah[si];
            al[m] = *(const short8v*)&Al[si];
        }
        #pragma unroll
        for (int nn = 0; nn < 4; ++nn) {
            int si = sw_sidx(wc + nn * 16 + (lane & 15), kk);
            bh[nn] = *(const short8v*)&Wh[si];
            bl[nn] = *(const short8v*)&Wl[si];
        }
        #pragma unroll
        for (int m = 0; m < 4; ++m)
            #pragma unroll
            for (int nn = 0; nn < 4; ++nn) {
                acc[m][nn] = __builtin_amdgcn_mfma_f32_16x16x32_bf16(ah[m], bh[nn], acc[m][nn], 0, 0, 0);
                acc[m][nn] = __builtin_amdgcn_mfma_f32_16x16x32_bf16(al[m], bh[nn], acc[m][nn], 0, 0, 0);
                acc[m][nn] = __builtin_amdgcn_mfma_f32_16x16x32_bf16(ah[m], bl[nn], acc[m][nn], 0, 0, 0);
            }
    }

    // epilogue: msc[(colr>>6)][(row)][colr&63]
    #pragma unroll
    for (int m = 0; m < 4; ++m) {
        #pragma unroll
        for (int j = 0; j < 4; ++j) {
            int row = rb + wr + m * 16 + (lane >> 4) * 4 + j;
            if (row < n) {
                float dv = dinv[row];
                #pragma unroll
                for (int nn = 0; nn < 4; ++nn) {
                    int colr = wc + nn * 16 + (lane & 15);
                    msc[((size_t)(colr >> 6) * (n + 1) + row) * 64 + (colr & 63)] =
                        f2bf(dv * acc[m][nn][j]);
                }
            }
        }
    }
}

// ---------------- feature-sliced aggregation, 2 slices x 64 cols ----------------

template <bool WF32>
__global__ __launch_bounds__(256) void agg_sl(const unsigned short* __restrict__ msc,
                                              const int* __restrict__ cnt,
                                              const unsigned short* __restrict__ col,
                                              const float* __restrict__ dinv,
                                              const float* __restrict__ bias,
                                              float* __restrict__ out,
                                              unsigned short* __restrict__ asl, int n) {
    int lane = threadIdx.x & 63;
    int g    = lane >> 3;    // group 0..7 -> node
    int l8   = lane & 7;     // 8-col chunk within 64-col slice
    int wid  = threadIdx.x >> 6;
    int p    = blockIdx.x & 1;
    int bi   = blockIdx.x >> 1;
    int nblk = gridDim.x >> 1;

    const unsigned short* msl = msc + (size_t)p * (n + 1) * 64;
    int cbase = p * 64 + l8 * 8;

    for (int i = bi * 32 + wid * 8 + g; i < n; i += nblk * 32) {
        float a0, a1, a2, a3, a4, a5, a6, a7;
        {   // self loop init
            short8v v = *(const short8v*)&msl[(size_t)i * 64 + l8 * 8];
            a0 = bf2f((unsigned short)v[0]); a1 = bf2f((unsigned short)v[1]);
            a2 = bf2f((unsigned short)v[2]); a3 = bf2f((unsigned short)v[3]);
            a4 = bf2f((unsigned short)v[4]); a5 = bf2f((unsigned short)v[5]);
            a6 = bf2f((unsigned short)v[6]); a7 = bf2f((unsigned short)v[7]);
        }
        int deg = cnt[i]; deg = (deg < SLOTS) ? deg : SLOTS;
        int degR = (deg + 7) & ~7; degR = (degR < SLOTS) ? degR : SLOTS;
        const unsigned short* crow = col + (size_t)i * SLOTS;
        for (int base = 0; base < degR; base += 8) {
            short8v ci = *(const short8v*)&crow[base];
            #pragma unroll
            for (int u = 0; u < 8; ++u) {
                unsigned j = (unsigned short)ci[u];
                short8v v = *(const short8v*)&msl[(size_t)j * 64 + l8 * 8];
                a0 += bf2f((unsigned short)v[0]); a1 += bf2f((unsigned short)v[1]);
                a2 += bf2f((unsigned short)v[2]); a3 += bf2f((unsigned short)v[3]);
                a4 += bf2f((unsigned short)v[4]); a5 += bf2f((unsigned short)v[5]);
                a6 += bf2f((unsigned short)v[6]); a7 += bf2f((unsigned short)v[7]);
            }
        }
        if (WF32) {
            float di = dinv[i];
            float4 b0 = *(const float4*)&bias[cbase];
            float4 b1 = *(const float4*)&bias[cbase + 4];
            floatx4 r0 = {fmaf(di, a0, b0.x), fmaf(di, a1, b0.y),
                          fmaf(di, a2, b0.z), fmaf(di, a3, b0.w)};
            floatx4 r1 = {fmaf(di, a4, b1.x), fmaf(di, a5, b1.y),
                          fmaf(di, a6, b1.z), fmaf(di, a7, b1.w)};
            floatx4* o4 = (floatx4*)&out[(size_t)i * D + cbase];
            o4[0] = r0;
            o4[1] = r1;
        } else {
            short8v r;
            r[0] = (short)f2bf(a0); r[1] = (short)f2bf(a1);
            r[2] = (short)f2bf(a2); r[3] = (short)f2bf(a3);
            r[4] = (short)f2bf(a4); r[5] = (short)f2bf(a5);
            r[6] = (short)f2bf(a6); r[7] = (short)f2bf(a7);
            *(short8v*)&asl[((size_t)p * n + i) * 64 + l8 * 8] = r;
        }
    }
}

// ---------------- LN pass ----------------

template <bool WF32OUT>
__global__ __launch_bounds__(256) void ln_kernel(const unsigned short* __restrict__ asl,
                                                 const float* __restrict__ dinv,
                                                 const float* __restrict__ bias,
                                                 const float* __restrict__ gamma,
                                                 const float* __restrict__ beta,
                                                 float* __restrict__ out,
                                                 unsigned short* __restrict__ oh,
                                                 unsigned short* __restrict__ ol, int n) {
    int lane = threadIdx.x & 63;
    int g    = lane >> 4;
    int l16  = lane & 15;
    int wid  = threadIdx.x >> 6;
    int i = blockIdx.x * 16 + wid * 4 + g;
    if (i >= n) return;

    short8v v = *(const short8v*)&asl[((size_t)(l16 >> 3) * n + i) * 64 + (l16 & 7) * 8];
    float di = dinv[i];
    float4 b0 = ((const float4*)bias)[l16 * 2];
    float4 b1 = ((const float4*)bias)[l16 * 2 + 1];
    float a[8];
    a[0] = fmaf(di, bf2f((unsigned short)v[0]), b0.x);
    a[1] = fmaf(di, bf2f((unsigned short)v[1]), b0.y);
    a[2] = fmaf(di, bf2f((unsigned short)v[2]), b0.z);
    a[3] = fmaf(di, bf2f((unsigned short)v[3]), b0.w);
    a[4] = fmaf(di, bf2f((unsigned short)v[4]), b1.x);
    a[5] = fmaf(di, bf2f((unsigned short)v[5]), b1.y);
    a[6] = fmaf(di, bf2f((unsigned short)v[6]), b1.z);
    a[7] = fmaf(di, bf2f((unsigned short)v[7]), b1.w);

    float s = 0.f, ss = 0.f;
    #pragma unroll
    for (int j = 0; j < 8; ++j) { s += a[j]; ss += a[j] * a[j]; }
    #pragma unroll
    for (int off = 1; off < 16; off <<= 1) {
        s  += __shfl_xor(s, off, 64);
        ss += __shfl_xor(ss, off, 64);
    }
    float mu   = s * (1.0f / D);
    float var  = ss * (1.0f / D) - mu * mu;
    float rstd = rsqrtf(var + EPS);

    float4 g0 = ((const float4*)gamma)[l16 * 2];
    float4 g1 = ((const float4*)gamma)[l16 * 2 + 1];
    float4 e0 = ((const float4*)beta)[l16 * 2];
    float4 e1 = ((const float4*)beta)[l16 * 2 + 1];
    float gv[8] = {g0.x, g0.y, g0.z, g0.w, g1.x, g1.y, g1.z, g1.w};
    float ev[8] = {e0.x, e0.y, e0.z, e0.w, e1.x, e1.y, e1.z, e1.w};
    #pragma unroll
    for (int j = 0; j < 8; ++j)
        a[j] = fmaxf((a[j] - mu) * rstd * gv[j] + ev[j], 0.f);

    if (WF32OUT) {
        floatx4 r0 = {a[0], a[1], a[2], a[3]};
        floatx4 r1 = {a[4], a[5], a[6], a[7]};
        floatx4* o4 = (floatx4*)out;
        o4[(size_t)i * 32 + l16 * 2]     = r0;
        o4[(size_t)i * 32 + l16 * 2 + 1] = r1;
    }
    short8v h, l;
    #pragma unroll
    for (int j = 0; j < 8; ++j) {
        unsigned short hb = f2bf(a[j]);
        h[j] = (short)hb;
        l[j] = (short)f2bf(a[j] - bf2f(hb));
    }
    *(short8v*)&oh[(size_t)i * D + l16 * 8] = h;
    *(short8v*)&ol[(size_t)i * D + l16 * 8] = l;
}

// ---------------- launch ----------------

static inline size_t align_up(size_t v, size_t a) { return (v + a - 1) & ~(a - 1); }

extern "C" void kernel_launch(void* const* d_in, const int* in_sizes, int n_in,
                              void* d_out, int out_size, void* d_ws, size_t ws_size,
                              hipStream_t stream) {
    const float* x  = (const float*)d_in[0];
    const int*   ei = (const int*)d_in[1];
    const float* W1 = (const float*)d_in[2];
    const float* b1 = (const float*)d_in[3];
    const float* W2 = (const float*)d_in[4];
    const float* b2 = (const float*)d_in[5];
    const float* W3 = (const float*)d_in[6];
    const float* b3 = (const float*)d_in[7];
    const float* g1  = (const float*)d_in[8];
    const float* be1 = (const float*)d_in[9];
    const float* g2  = (const float*)d_in[10];
    const float* be2 = (const float*)d_in[11];

    int N = in_sizes[0] / D;
    int E = in_sizes[1] / 2;
    const int* srcv = ei;
    const int* dstv = ei + E;

    float* out   = (float*)d_out;
    float* h2out = out;
    float* h3out = out + (size_t)N * D;

    char* w = (char*)d_ws;
    int* cnt = (int*)w;      w += align_up((size_t)N * 4, 256);
    float* dinv = (float*)w; w += align_up((size_t)N * 4, 256);
    unsigned short* wt = (unsigned short*)w;   w += align_up((size_t)3 * 2 * 16384 * 2, 256);
    unsigned short* colA = (unsigned short*)w; w += align_up((size_t)N * SLOTS * 2, 256);
    unsigned short* msc = (unsigned short*)w;  w += align_up((size_t)(N + 1) * D * 2, 256);
    unsigned short* asl = (unsigned short*)w;  w += align_up((size_t)N * D * 2, 256);
    unsigned short* hh = (unsigned short*)w;   w += align_up((size_t)N * D * 2, 256);
    unsigned short* hl = (unsigned short*)w;   w += align_up((size_t)N * D * 2, 256);

    wprep_kernel<<<192, 256, 0, stream>>>(W1, W2, W3, wt);
    hipMemsetAsync(cnt, 0, (size_t)N * sizeof(int), stream);
    zdum_kernel<<<1, 128, 0, stream>>>(msc, N);
    build_kernel<<<2048, 256, 0, stream>>>(srcv, dstv, cnt, colA, E, N);
    paddinv_kernel<<<(N + 255) / 256, 256, 0, stream>>>(cnt, colA, dinv, N, N);

    int gemmGrid = (N + 127) / 128;
    int aggGrid  = 2048;
    int lnGrid   = (N + 15) / 16;

    const unsigned short* wt1h = wt + 0 * 16384;
    const unsigned short* wt1l = wt + 1 * 16384;
    const unsigned short* wt2h = wt + 2 * 16384;
    const unsigned short* wt2l = wt + 3 * 16384;
    const unsigned short* wt3h = wt + 4 * 16384;
    const unsigned short* wt3l = wt + 5 * 16384;

    // layer 1
    gemm_kernel<0><<<gemmGrid, 256, 0, stream>>>(x, nullptr, nullptr, wt1h, wt1l, dinv, msc, N);
    agg_sl<false><<<aggGrid, 256, 0, stream>>>(msc, cnt, colA, dinv, b1, nullptr, asl, N);
    ln_kernel<false><<<lnGrid, 256, 0, stream>>>(asl, dinv, b1, g1, be1, nullptr, hh, hl, N);
    // layer 2
    gemm_kernel<1><<<gemmGrid, 256, 0, stream>>>(nullptr, hh, hl, wt2h, wt2l, dinv, msc, N);
    agg_sl<false><<<aggGrid, 256, 0, stream>>>(msc, cnt, colA, dinv, b2, nullptr, asl, N);
    ln_kernel<true><<<lnGrid, 256, 0, stream>>>(asl, dinv, b2, g2, be2, h2out, hh, hl, N);
    // layer 3
    gemm_kernel<1><<<gemmGrid, 256, 0, stream>>>(nullptr, hh, hl, wt3h, wt3l, dinv, msc, N);
    agg_sl<true><<<aggGrid, 256, 0, stream>>>(msc, cnt, colA, dinv, b3, h3out, nullptr, N);
}

// Round 16
// 280.174 us; speedup vs baseline: 2.0575x; 1.0151x over previous
//
#include <hip/hip_runtime.h>
#include <hip/hip_bf16.h>

#define D 128
#define EPS 1e-5f
#define SLOTS 128

typedef __attribute__((ext_vector_type(8))) short short8v;
typedef __attribute__((ext_vector_type(4))) float floatx4;
typedef __attribute__((ext_vector_type(4))) int int4v;

__device__ __forceinline__ unsigned short f2bf(float f) {
    union { float f; unsigned u; } v; v.f = f;
    unsigned r = (v.u + 0x7FFF + ((v.u >> 16) & 1)) >> 16;
    return (unsigned short)r;
}
__device__ __forceinline__ float bf2f(unsigned short h) {
    union { unsigned u; float f; } v; v.u = ((unsigned)h) << 16;
    return v.f;
}

// ---------------- merged CSR build: one pass, fixed-slot table, NP=4 ----------------

__global__ __launch_bounds__(256) void build_kernel(const int* __restrict__ src,
                                                    const int* __restrict__ dst,
                                                    int* __restrict__ cnt,
                                                    unsigned short* __restrict__ col,
                                                    int E, int N) {
    int p   = blockIdx.x & 3;
    int lo  = (int)((long long)p * N / 4);
    int hi  = (int)((long long)(p + 1) * N / 4);
    int blk = blockIdx.x >> 2;
    int stride = (gridDim.x >> 2) * 256;
    int E4 = E >> 2;
    const int4v* dst4 = (const int4v*)dst;
    const int4v* src4 = (const int4v*)src;
    for (int e = blk * 256 + (int)threadIdx.x; e < E4; e += stride) {
        int4v d = __builtin_nontemporal_load(dst4 + e);
        int4v s = __builtin_nontemporal_load(src4 + e);
        #pragma unroll
        for (int u = 0; u < 4; ++u) {
            int dd = d[u];
            if (dd >= lo && dd < hi) {
                int pos = atomicAdd(&cnt[dd], 1);
                if (pos < SLOTS) col[(size_t)dd * SLOTS + pos] = (unsigned short)s[u];
            }
        }
    }
    if (p == 0 && blk == 0 && threadIdx.x < (unsigned)(E & 3)) {
        int e = E4 * 4 + (int)threadIdx.x;
        int d = dst[e];
        int pos = atomicAdd(&cnt[d], 1);
        if (pos < SLOTS) col[(size_t)d * SLOTS + pos] = (unsigned short)src[e];
    }
}

// fused pad (to x8 with dummy index N) + dinv
__global__ __launch_bounds__(256) void paddinv_kernel(const int* __restrict__ cnt,
                                                      unsigned short* __restrict__ col,
                                                      float* __restrict__ dinv,
                                                      int n, int N) {
    int i = blockIdx.x * 256 + threadIdx.x;
    if (i >= n) return;
    int deg0 = cnt[i];
    dinv[i] = rsqrtf((float)(deg0 + 1));
    int deg = (deg0 < SLOTS) ? deg0 : SLOTS;
    int end = (deg + 7) & ~7; end = (end < SLOTS) ? end : SLOTS;
    unsigned short* c = col + (size_t)i * SLOTS;
    for (int s = deg; s < end; ++s) c[s] = (unsigned short)N;
}

// zero the dummy row N in both 64-col slices of msc
__global__ void zdum_kernel(unsigned short* __restrict__ msc, int n) {
    int t = threadIdx.x;   // 128 threads: slice t>>6, col t&63
    msc[((size_t)(t >> 6) * (n + 1) + n) * 64 + (t & 63)] = 0;
}

// ---------------- W precompute: transpose + bf16 hi/lo split ----------------

__global__ void wprep_kernel(const float* __restrict__ W1, const float* __restrict__ W2,
                             const float* __restrict__ W3, unsigned short* __restrict__ wt) {
    int gid = blockIdx.x * 256 + threadIdx.x;   // 0 .. 3*16384
    int z = gid >> 14;
    int r = gid & 16383;
    int c = r >> 7, k = r & 127;
    const float* W = (z == 0) ? W1 : ((z == 1) ? W2 : W3);
    float v = W[k * D + c];
    unsigned short hi = f2bf(v);
    unsigned short lo = f2bf(v - bf2f(hi));
    wt[(size_t)(z * 2 + 0) * 16384 + r] = hi;
    wt[(size_t)(z * 2 + 1) * 16384 + r] = lo;
}

// ---------------- MFMA GEMM -> sliced msc: msc[sl(2)][row][64], pre-scaled by dinv ----
// A (hi/lo) staged in LDS (64 KiB -> 2 blocks/CU); W read directly from global
// (wt is 64KB, L2-resident, shared by all blocks). 16B/lane W loads, 4-lane
// contiguous 64B segments.

__device__ __forceinline__ int sw_sidx(int row, int k) {   // short index, XOR-swizzled
    int byte = row * 256 + k * 2;
    byte ^= (row & 7) << 4;
    return byte >> 1;
}

template <int AMODE>
__global__ __launch_bounds__(256, 2) void gemm_kernel(const float* __restrict__ A,
                                                      const unsigned short* __restrict__ Agh,
                                                      const unsigned short* __restrict__ Agl,
                                                      const unsigned short* __restrict__ wt_hi,
                                                      const unsigned short* __restrict__ wt_lo,
                                                      const float* __restrict__ dinv,
                                                      unsigned short* __restrict__ msc, int n) {
    __shared__ short lds[2 * 16384];
    short* Ah = lds;
    short* Al = lds + 16384;

    const int t = threadIdx.x;
    const int rb = blockIdx.x * 128;

    // stage A with fp32 -> bf16 hi/lo conversion (or pre-split copy)
    #pragma unroll
    for (int p = 0; p < 8; ++p) {
        int chunk = p * 256 + t;
        int r = chunk >> 4, k0 = (chunk & 15) << 3;
        int row = rb + r;
        int rowc = (row < n) ? row : (n - 1);
        int si = sw_sidx(r, k0);
        if (AMODE == 0) {
            float4 f0 = *(const float4*)&A[(size_t)rowc * D + k0];
            float4 f1 = *(const float4*)&A[(size_t)rowc * D + k0 + 4];
            float fv[8] = {f0.x, f0.y, f0.z, f0.w, f1.x, f1.y, f1.z, f1.w};
            short8v hi, lo;
            #pragma unroll
            for (int j = 0; j < 8; ++j) {
                unsigned short h = f2bf(fv[j]);
                hi[j] = (short)h;
                lo[j] = (short)f2bf(fv[j] - bf2f(h));
            }
            *(short8v*)&Ah[si] = hi;
            *(short8v*)&Al[si] = lo;
        } else {
            *(short8v*)&Ah[si] = *(const short8v*)&Agh[(size_t)rowc * D + k0];
            *(short8v*)&Al[si] = *(const short8v*)&Agl[(size_t)rowc * D + k0];
        }
    }
    __syncthreads();

    const int lane = t & 63;
    const int wid  = t >> 6;
    const int wr = (wid & 1) * 64;
    const int wc = (wid >> 1) * 64;

    floatx4 acc[4][4];
    #pragma unroll
    for (int m = 0; m < 4; ++m)
        #pragma unroll
        for (int nn = 0; nn < 4; ++nn)
            acc[m][nn] = (floatx4){0.f, 0.f, 0.f, 0.f};

    #pragma unroll
    for (int ks = 0; ks < 4; ++ks) {
        const int kk = ks * 32 + (lane >> 4) * 8;
        short8v ah[4], al[4], bh[4], bl[4];
        #pragma unroll
        for (int nn = 0; nn < 4; ++nn) {   // W from global (L2)
            int c = wc + nn * 16 + (lane & 15);
            bh[nn] = *(const short8v*)&wt_hi[c * D + kk];
            bl[nn] = *(const short8v*)&wt_lo[c * D + kk];
        }
        #pragma unroll
        for (int m = 0; m < 4; ++m) {
            int si = sw_sidx(wr + m * 16 + (lane & 15), kk);
            ah[m] = *(const short8v*)&Ah[si];
            al[m] = *(const short8v*)&Al[si];
        }
        #pragma unroll
        for (int m = 0; m < 4; ++m)
            #pragma unroll
            for (int nn = 0; nn < 4; ++nn) {
                acc[m][nn] = __builtin_amdgcn_mfma_f32_16x16x32_bf16(ah[m], bh[nn], acc[m][nn], 0, 0, 0);
                acc[m][nn] = __builtin_amdgcn_mfma_f32_16x16x32_bf16(al[m], bh[nn], acc[m][nn], 0, 0, 0);
                acc[m][nn] = __builtin_amdgcn_mfma_f32_16x16x32_bf16(ah[m], bl[nn], acc[m][nn], 0, 0, 0);
            }
    }

    // epilogue: msc[(colr>>6)][(row)][colr&63]
    #pragma unroll
    for (int m = 0; m < 4; ++m) {
        #pragma unroll
        for (int j = 0; j < 4; ++j) {
            int row = rb + wr + m * 16 + (lane >> 4) * 4 + j;
            if (row < n) {
                float dv = dinv[row];
                #pragma unroll
                for (int nn = 0; nn < 4; ++nn) {
                    int colr = wc + nn * 16 + (lane & 15);
                    msc[((size_t)(colr >> 6) * (n + 1) + row) * 64 + (colr & 63)] =
                        f2bf(dv * acc[m][nn][j]);
                }
            }
        }
    }
}

// ---------------- feature-sliced aggregation, 2 slices x 64 cols ----------------

template <bool WF32>
__global__ __launch_bounds__(256) void agg_sl(const unsigned short* __restrict__ msc,
                                              const int* __restrict__ cnt,
                                              const unsigned short* __restrict__ col,
                                              const float* __restrict__ dinv,
                                              const float* __restrict__ bias,
                                              float* __restrict__ out,
                                              unsigned short* __restrict__ asl, int n) {
    int lane = threadIdx.x & 63;
    int g    = lane >> 3;    // group 0..7 -> node
    int l8   = lane & 7;     // 8-col chunk within 64-col slice
    int wid  = threadIdx.x >> 6;
    int p    = blockIdx.x & 1;
    int bi   = blockIdx.x >> 1;
    int nblk = gridDim.x >> 1;

    const unsigned short* msl = msc + (size_t)p * (n + 1) * 64;
    int cbase = p * 64 + l8 * 8;

    for (int i = bi * 32 + wid * 8 + g; i < n; i += nblk * 32) {
        float a0, a1, a2, a3, a4, a5, a6, a7;
        {   // self loop init
            short8v v = *(const short8v*)&msl[(size_t)i * 64 + l8 * 8];
            a0 = bf2f((unsigned short)v[0]); a1 = bf2f((unsigned short)v[1]);
            a2 = bf2f((unsigned short)v[2]); a3 = bf2f((unsigned short)v[3]);
            a4 = bf2f((unsigned short)v[4]); a5 = bf2f((unsigned short)v[5]);
            a6 = bf2f((unsigned short)v[6]); a7 = bf2f((unsigned short)v[7]);
        }
        int deg = cnt[i]; deg = (deg < SLOTS) ? deg : SLOTS;
        int degR = (deg + 7) & ~7; degR = (degR < SLOTS) ? degR : SLOTS;
        const unsigned short* crow = col + (size_t)i * SLOTS;
        for (int base = 0; base < degR; base += 8) {
            short8v ci = *(const short8v*)&crow[base];
            #pragma unroll
            for (int u = 0; u < 8; ++u) {
                unsigned j = (unsigned short)ci[u];
                short8v v = *(const short8v*)&msl[(size_t)j * 64 + l8 * 8];
                a0 += bf2f((unsigned short)v[0]); a1 += bf2f((unsigned short)v[1]);
                a2 += bf2f((unsigned short)v[2]); a3 += bf2f((unsigned short)v[3]);
                a4 += bf2f((unsigned short)v[4]); a5 += bf2f((unsigned short)v[5]);
                a6 += bf2f((unsigned short)v[6]); a7 += bf2f((unsigned short)v[7]);
            }
        }
        if (WF32) {
            float di = dinv[i];
            float4 b0 = *(const float4*)&bias[cbase];
            float4 b1 = *(const float4*)&bias[cbase + 4];
            floatx4 r0 = {fmaf(di, a0, b0.x), fmaf(di, a1, b0.y),
                          fmaf(di, a2, b0.z), fmaf(di, a3, b0.w)};
            floatx4 r1 = {fmaf(di, a4, b1.x), fmaf(di, a5, b1.y),
                          fmaf(di, a6, b1.z), fmaf(di, a7, b1.w)};
            floatx4* o4 = (floatx4*)&out[(size_t)i * D + cbase];
            o4[0] = r0;
            o4[1] = r1;
        } else {
            short8v r;
            r[0] = (short)f2bf(a0); r[1] = (short)f2bf(a1);
            r[2] = (short)f2bf(a2); r[3] = (short)f2bf(a3);
            r[4] = (short)f2bf(a4); r[5] = (short)f2bf(a5);
            r[6] = (short)f2bf(a6); r[7] = (short)f2bf(a7);
            *(short8v*)&asl[((size_t)p * n + i) * 64 + l8 * 8] = r;
        }
    }
}

// ---------------- LN pass ----------------

template <bool WF32OUT>
__global__ __launch_bounds__(256) void ln_kernel(const unsigned short* __restrict__ asl,
                                                 const float* __restrict__ dinv,
                                                 const float* __restrict__ bias,
                                                 const float* __restrict__ gamma,
                                                 const float* __restrict__ beta,
                                                 float* __restrict__ out,
                                                 unsigned short* __restrict__ oh,
                                                 unsigned short* __restrict__ ol, int n) {
    int lane = threadIdx.x & 63;
    int g    = lane >> 4;
    int l16  = lane & 15;
    int wid  = threadIdx.x >> 6;
    int i = blockIdx.x * 16 + wid * 4 + g;
    if (i >= n) return;

    short8v v = *(const short8v*)&asl[((size_t)(l16 >> 3) * n + i) * 64 + (l16 & 7) * 8];
    float di = dinv[i];
    float4 b0 = ((const float4*)bias)[l16 * 2];
    float4 b1 = ((const float4*)bias)[l16 * 2 + 1];
    float a[8];
    a[0] = fmaf(di, bf2f((unsigned short)v[0]), b0.x);
    a[1] = fmaf(di, bf2f((unsigned short)v[1]), b0.y);
    a[2] = fmaf(di, bf2f((unsigned short)v[2]), b0.z);
    a[3] = fmaf(di, bf2f((unsigned short)v[3]), b0.w);
    a[4] = fmaf(di, bf2f((unsigned short)v[4]), b1.x);
    a[5] = fmaf(di, bf2f((unsigned short)v[5]), b1.y);
    a[6] = fmaf(di, bf2f((unsigned short)v[6]), b1.z);
    a[7] = fmaf(di, bf2f((unsigned short)v[7]), b1.w);

    float s = 0.f, ss = 0.f;
    #pragma unroll
    for (int j = 0; j < 8; ++j) { s += a[j]; ss += a[j] * a[j]; }
    #pragma unroll
    for (int off = 1; off < 16; off <<= 1) {
        s  += __shfl_xor(s, off, 64);
        ss += __shfl_xor(ss, off, 64);
    }
    float mu   = s * (1.0f / D);
    float var  = ss * (1.0f / D) - mu * mu;
    float rstd = rsqrtf(var + EPS);

    float4 g0 = ((const float4*)gamma)[l16 * 2];
    float4 g1 = ((const float4*)gamma)[l16 * 2 + 1];
    float4 e0 = ((const float4*)beta)[l16 * 2];
    float4 e1 = ((const float4*)beta)[l16 * 2 + 1];
    float gv[8] = {g0.x, g0.y, g0.z, g0.w, g1.x, g1.y, g1.z, g1.w};
    float ev[8] = {e0.x, e0.y, e0.z, e0.w, e1.x, e1.y, e1.z, e1.w};
    #pragma unroll
    for (int j = 0; j < 8; ++j)
        a[j] = fmaxf((a[j] - mu) * rstd * gv[j] + ev[j], 0.f);

    if (WF32OUT) {
        floatx4 r0 = {a[0], a[1], a[2], a[3]};
        floatx4 r1 = {a[4], a[5], a[6], a[7]};
        floatx4* o4 = (floatx4*)out;
        o4[(size_t)i * 32 + l16 * 2]     = r0;
        o4[(size_t)i * 32 + l16 * 2 + 1] = r1;
    }
    short8v h, l;
    #pragma unroll
    for (int j = 0; j < 8; ++j) {
        unsigned short hb = f2bf(a[j]);
        h[j] = (short)hb;
        l[j] = (short)f2bf(a[j] - bf2f(hb));
    }
    *(short8v*)&oh[(size_t)i * D + l16 * 8] = h;
    *(short8v*)&ol[(size_t)i * D + l16 * 8] = l;
}

// ---------------- launch ----------------

static inline size_t align_up(size_t v, size_t a) { return (v + a - 1) & ~(a - 1); }

extern "C" void kernel_launch(void* const* d_in, const int* in_sizes, int n_in,
                              void* d_out, int out_size, void* d_ws, size_t ws_size,
                              hipStream_t stream) {
    const float* x  = (const float*)d_in[0];
    const int*   ei = (const int*)d_in[1];
    const float* W1 = (const float*)d_in[2];
    const float* b1 = (const float*)d_in[3];
    const float* W2 = (const float*)d_in[4];
    const float* b2 = (const float*)d_in[5];
    const float* W3 = (const float*)d_in[6];
    const float* b3 = (const float*)d_in[7];
    const float* g1  = (const float*)d_in[8];
    const float* be1 = (const float*)d_in[9];
    const float* g2  = (const float*)d_in[10];
    const float* be2 = (const float*)d_in[11];

    int N = in_sizes[0] / D;
    int E = in_sizes[1] / 2;
    const int* srcv = ei;
    const int* dstv = ei + E;

    float* out   = (float*)d_out;
    float* h2out = out;
    float* h3out = out + (size_t)N * D;

    char* w = (char*)d_ws;
    int* cnt = (int*)w;      w += align_up((size_t)N * 4, 256);
    float* dinv = (float*)w; w += align_up((size_t)N * 4, 256);
    unsigned short* wt = (unsigned short*)w;   w += align_up((size_t)3 * 2 * 16384 * 2, 256);
    unsigned short* colA = (unsigned short*)w; w += align_up((size_t)N * SLOTS * 2, 256);
    unsigned short* msc = (unsigned short*)w;  w += align_up((size_t)(N + 1) * D * 2, 256);
    unsigned short* asl = (unsigned short*)w;  w += align_up((size_t)N * D * 2, 256);
    unsigned short* hh = (unsigned short*)w;   w += align_up((size_t)N * D * 2, 256);
    unsigned short* hl = (unsigned short*)w;   w += align_up((size_t)N * D * 2, 256);

    wprep_kernel<<<192, 256, 0, stream>>>(W1, W2, W3, wt);
    hipMemsetAsync(cnt, 0, (size_t)N * sizeof(int), stream);
    zdum_kernel<<<1, 128, 0, stream>>>(msc, N);
    build_kernel<<<2048, 256, 0, stream>>>(srcv, dstv, cnt, colA, E, N);
    paddinv_kernel<<<(N + 255) / 256, 256, 0, stream>>>(cnt, colA, dinv, N, N);

    int gemmGrid = (N + 127) / 128;
    int aggGrid  = 2048;
    int lnGrid   = (N + 15) / 16;

    const unsigned short* wt1h = wt + 0 * 16384;
    const unsigned short* wt1l = wt + 1 * 16384;
    const unsigned short* wt2h = wt + 2 * 16384;
    const unsigned short* wt2l = wt + 3 * 16384;
    const unsigned short* wt3h = wt + 4 * 16384;
    const unsigned short* wt3l = wt + 5 * 16384;

    // layer 1
    gemm_kernel<0><<<gemmGrid, 256, 0, stream>>>(x, nullptr, nullptr, wt1h, wt1l, dinv, msc, N);
    agg_sl<false><<<aggGrid, 256, 0, stream>>>(msc, cnt, colA, dinv, b1, nullptr, asl, N);
    ln_kernel<false><<<lnGrid, 256, 0, stream>>>(asl, dinv, b1, g1, be1, nullptr, hh, hl, N);
    // layer 2
    gemm_kernel<1><<<gemmGrid, 256, 0, stream>>>(nullptr, hh, hl, wt2h, wt2l, dinv, msc, N);
    agg_sl<false><<<aggGrid, 256, 0, stream>>>(msc, cnt, colA, dinv, b2, nullptr, asl, N);
    ln_kernel<true><<<lnGrid, 256, 0, stream>>>(asl, dinv, b2, g2, be2, h2out, hh, hl, N);
    // layer 3
    gemm_kernel<1><<<gemmGrid, 256, 0, stream>>>(nullptr, hh, hl, wt3h, wt3l, dinv, msc, N);
    agg_sl<true><<<aggGrid, 256, 0, stream>>>(msc, cnt, colA, dinv, b3, h3out, nullptr, N);
}

// Round 17
// 273.467 us; speedup vs baseline: 2.1080x; 1.0245x over previous
//
#include <hip/hip_runtime.h>
#include <hip/hip_bf16.h>

#define D 128
#define EPS 1e-5f
#define SLOTS 128

typedef __attribute__((ext_vector_type(8))) short short8v;
typedef __attribute__((ext_vector_type(4))) float floatx4;
typedef __attribute__((ext_vector_type(4))) int int4v;

__device__ __forceinline__ unsigned short f2bf(float f) {
    union { float f; unsigned u; } v; v.f = f;
    unsigned r = (v.u + 0x7FFF + ((v.u >> 16) & 1)) >> 16;
    return (unsigned short)r;
}
__device__ __forceinline__ float bf2f(unsigned short h) {
    union { unsigned u; float f; } v; v.u = ((unsigned)h) << 16;
    return v.f;
}

// ---------------- merged CSR build: one pass, fixed-slot table, NP=4 ----------------

__global__ __launch_bounds__(256) void build_kernel(const int* __restrict__ src,
                                                    const int* __restrict__ dst,
                                                    int* __restrict__ cnt,
                                                    unsigned short* __restrict__ col,
                                                    int E, int N) {
    int p   = blockIdx.x & 3;
    int lo  = (int)((long long)p * N / 4);
    int hi  = (int)((long long)(p + 1) * N / 4);
    int blk = blockIdx.x >> 2;
    int stride = (gridDim.x >> 2) * 256;
    int E4 = E >> 2;
    const int4v* dst4 = (const int4v*)dst;
    const int4v* src4 = (const int4v*)src;
    for (int e = blk * 256 + (int)threadIdx.x; e < E4; e += stride) {
        int4v d = __builtin_nontemporal_load(dst4 + e);
        int4v s = __builtin_nontemporal_load(src4 + e);
        #pragma unroll
        for (int u = 0; u < 4; ++u) {
            int dd = d[u];
            if (dd >= lo && dd < hi) {
                int pos = atomicAdd(&cnt[dd], 1);
                if (pos < SLOTS) col[(size_t)dd * SLOTS + pos] = (unsigned short)s[u];
            }
        }
    }
    if (p == 0 && blk == 0 && threadIdx.x < (unsigned)(E & 3)) {
        int e = E4 * 4 + (int)threadIdx.x;
        int d = dst[e];
        int pos = atomicAdd(&cnt[d], 1);
        if (pos < SLOTS) col[(size_t)d * SLOTS + pos] = (unsigned short)src[e];
    }
}

// fused pad (to x8 with dummy index N) + dinv
__global__ __launch_bounds__(256) void paddinv_kernel(const int* __restrict__ cnt,
                                                      unsigned short* __restrict__ col,
                                                      float* __restrict__ dinv,
                                                      int n, int N) {
    int i = blockIdx.x * 256 + threadIdx.x;
    if (i >= n) return;
    int deg0 = cnt[i];
    dinv[i] = rsqrtf((float)(deg0 + 1));
    int deg = (deg0 < SLOTS) ? deg0 : SLOTS;
    int end = (deg + 7) & ~7; end = (end < SLOTS) ? end : SLOTS;
    unsigned short* c = col + (size_t)i * SLOTS;
    for (int s = deg; s < end; ++s) c[s] = (unsigned short)N;
}

// zero the dummy row N in both 64-col slices of msc
__global__ void zdum_kernel(unsigned short* __restrict__ msc, int n) {
    int t = threadIdx.x;   // 128 threads: slice t>>6, col t&63
    msc[((size_t)(t >> 6) * (n + 1) + n) * 64 + (t & 63)] = 0;
}

// ---------------- W precompute: transpose + bf16 hi/lo split ----------------

__global__ void wprep_kernel(const float* __restrict__ W1, const float* __restrict__ W2,
                             const float* __restrict__ W3, unsigned short* __restrict__ wt) {
    int gid = blockIdx.x * 256 + threadIdx.x;   // 0 .. 3*16384
    int z = gid >> 14;
    int r = gid & 16383;
    int c = r >> 7, k = r & 127;
    const float* W = (z == 0) ? W1 : ((z == 1) ? W2 : W3);
    float v = W[k * D + c];
    unsigned short hi = f2bf(v);
    unsigned short lo = f2bf(v - bf2f(hi));
    wt[(size_t)(z * 2 + 0) * 16384 + r] = hi;
    wt[(size_t)(z * 2 + 1) * 16384 + r] = lo;
}

// ---------------- MFMA GEMM -> sliced msc: msc[sl(2)][row][64], pre-scaled by dinv ----
// AMODE 0: A = fp32 x (convert+split on stage).
// AMODE 2: A = LN(prev-layer sums): read asl bf16, apply dinv+bias+LN+ReLU in
//          staging (16-lane-group shfl reduce), split to hi/lo in LDS.
//          If WRITEH2: also emit the fp32 LN output (h2) to h2out.
// W read directly from global (64KB, L2-resident). LDS 64 KiB -> 2 blocks/CU.

__device__ __forceinline__ int sw_sidx(int row, int k) {   // short index, XOR-swizzled
    int byte = row * 256 + k * 2;
    byte ^= (row & 7) << 4;
    return byte >> 1;
}

template <int AMODE, bool WRITEH2>
__global__ __launch_bounds__(256, 2) void gemm_kernel(const float* __restrict__ A,
                                                      const unsigned short* __restrict__ aslin,
                                                      const unsigned short* __restrict__ wt_hi,
                                                      const unsigned short* __restrict__ wt_lo,
                                                      const float* __restrict__ dinv,
                                                      const float* __restrict__ bprev,
                                                      const float* __restrict__ gprev,
                                                      const float* __restrict__ beprev,
                                                      float* __restrict__ h2out,
                                                      unsigned short* __restrict__ msc, int n) {
    __shared__ short lds[2 * 16384];
    short* Ah = lds;
    short* Al = lds + 16384;

    const int t = threadIdx.x;
    const int rb = blockIdx.x * 128;
    const int lane = t & 63;

    #pragma unroll
    for (int p = 0; p < 8; ++p) {
        int chunk = p * 256 + t;
        int r = chunk >> 4, k0 = (chunk & 15) << 3;
        int row = rb + r;
        int rowc = (row < n) ? row : (n - 1);
        int si = sw_sidx(r, k0);
        if (AMODE == 0) {
            float4 f0 = *(const float4*)&A[(size_t)rowc * D + k0];
            float4 f1 = *(const float4*)&A[(size_t)rowc * D + k0 + 4];
            float fv[8] = {f0.x, f0.y, f0.z, f0.w, f1.x, f1.y, f1.z, f1.w};
            short8v hi, lo;
            #pragma unroll
            for (int j = 0; j < 8; ++j) {
                unsigned short h = f2bf(fv[j]);
                hi[j] = (short)h;
                lo[j] = (short)f2bf(fv[j] - bf2f(h));
            }
            *(short8v*)&Ah[si] = hi;
            *(short8v*)&Al[si] = lo;
        } else {
            // fused LN staging: a = relu(LN(dinv*sum + b)) computed here
            short8v v = *(const short8v*)&aslin[((size_t)(k0 >> 6) * n + rowc) * 64 + (k0 & 63)];
            float di = dinv[rowc];
            float4 b0 = *(const float4*)&bprev[k0];
            float4 b1 = *(const float4*)&bprev[k0 + 4];
            float a[8];
            a[0] = fmaf(di, bf2f((unsigned short)v[0]), b0.x);
            a[1] = fmaf(di, bf2f((unsigned short)v[1]), b0.y);
            a[2] = fmaf(di, bf2f((unsigned short)v[2]), b0.z);
            a[3] = fmaf(di, bf2f((unsigned short)v[3]), b0.w);
            a[4] = fmaf(di, bf2f((unsigned short)v[4]), b1.x);
            a[5] = fmaf(di, bf2f((unsigned short)v[5]), b1.y);
            a[6] = fmaf(di, bf2f((unsigned short)v[6]), b1.z);
            a[7] = fmaf(di, bf2f((unsigned short)v[7]), b1.w);
            float s = 0.f, ss = 0.f;
            #pragma unroll
            for (int j = 0; j < 8; ++j) { s += a[j]; ss += a[j] * a[j]; }
            #pragma unroll
            for (int off = 1; off < 16; off <<= 1) {   // 16 lanes share one row
                s  += __shfl_xor(s, off, 64);
                ss += __shfl_xor(ss, off, 64);
            }
            float mu   = s * (1.0f / D);
            float var  = ss * (1.0f / D) - mu * mu;
            float rstd = rsqrtf(var + EPS);
            float4 g0 = *(const float4*)&gprev[k0];
            float4 g1 = *(const float4*)&gprev[k0 + 4];
            float4 e0 = *(const float4*)&beprev[k0];
            float4 e1 = *(const float4*)&beprev[k0 + 4];
            float gv[8] = {g0.x, g0.y, g0.z, g0.w, g1.x, g1.y, g1.z, g1.w};
            float ev[8] = {e0.x, e0.y, e0.z, e0.w, e1.x, e1.y, e1.z, e1.w};
            #pragma unroll
            for (int j = 0; j < 8; ++j)
                a[j] = fmaxf((a[j] - mu) * rstd * gv[j] + ev[j], 0.f);
            if (WRITEH2 && row < n) {
                floatx4 r0 = {a[0], a[1], a[2], a[3]};
                floatx4 r1 = {a[4], a[5], a[6], a[7]};
                *(floatx4*)&h2out[(size_t)row * D + k0]     = r0;
                *(floatx4*)&h2out[(size_t)row * D + k0 + 4] = r1;
            }
            short8v hi, lo;
            #pragma unroll
            for (int j = 0; j < 8; ++j) {
                unsigned short h = f2bf(a[j]);
                hi[j] = (short)h;
                lo[j] = (short)f2bf(a[j] - bf2f(h));
            }
            *(short8v*)&Ah[si] = hi;
            *(short8v*)&Al[si] = lo;
        }
    }
    __syncthreads();

    const int wid  = t >> 6;
    const int wr = (wid & 1) * 64;
    const int wc = (wid >> 1) * 64;

    floatx4 acc[4][4];
    #pragma unroll
    for (int m = 0; m < 4; ++m)
        #pragma unroll
        for (int nn = 0; nn < 4; ++nn)
            acc[m][nn] = (floatx4){0.f, 0.f, 0.f, 0.f};

    #pragma unroll
    for (int ks = 0; ks < 4; ++ks) {
        const int kk = ks * 32 + (lane >> 4) * 8;
        short8v ah[4], al[4], bh[4], bl[4];
        #pragma unroll
        for (int nn = 0; nn < 4; ++nn) {   // W from global (L2)
            int c = wc + nn * 16 + (lane & 15);
            bh[nn] = *(const short8v*)&wt_hi[c * D + kk];
            bl[nn] = *(const short8v*)&wt_lo[c * D + kk];
        }
        #pragma unroll
        for (int m = 0; m < 4; ++m) {
            int si = sw_sidx(wr + m * 16 + (lane & 15), kk);
            ah[m] = *(const short8v*)&Ah[si];
            al[m] = *(const short8v*)&Al[si];
        }
        #pragma unroll
        for (int m = 0; m < 4; ++m)
            #pragma unroll
            for (int nn = 0; nn < 4; ++nn) {
                acc[m][nn] = __builtin_amdgcn_mfma_f32_16x16x32_bf16(ah[m], bh[nn], acc[m][nn], 0, 0, 0);
                acc[m][nn] = __builtin_amdgcn_mfma_f32_16x16x32_bf16(al[m], bh[nn], acc[m][nn], 0, 0, 0);
                acc[m][nn] = __builtin_amdgcn_mfma_f32_16x16x32_bf16(ah[m], bl[nn], acc[m][nn], 0, 0, 0);
            }
    }

    // epilogue: msc[(colr>>6)][(row)][colr&63]
    #pragma unroll
    for (int m = 0; m < 4; ++m) {
        #pragma unroll
        for (int j = 0; j < 4; ++j) {
            int row = rb + wr + m * 16 + (lane >> 4) * 4 + j;
            if (row < n) {
                float dv = dinv[row];
                #pragma unroll
                for (int nn = 0; nn < 4; ++nn) {
                    int colr = wc + nn * 16 + (lane & 15);
                    msc[((size_t)(colr >> 6) * (n + 1) + row) * 64 + (colr & 63)] =
                        f2bf(dv * acc[m][nn][j]);
                }
            }
        }
    }
}

// ---------------- feature-sliced aggregation, 2 slices x 64 cols ----------------

template <bool WF32>
__global__ __launch_bounds__(256) void agg_sl(const unsigned short* __restrict__ msc,
                                              const int* __restrict__ cnt,
                                              const unsigned short* __restrict__ col,
                                              const float* __restrict__ dinv,
                                              const float* __restrict__ bias,
                                              float* __restrict__ out,
                                              unsigned short* __restrict__ asl, int n) {
    int lane = threadIdx.x & 63;
    int g    = lane >> 3;    // group 0..7 -> node
    int l8   = lane & 7;     // 8-col chunk within 64-col slice
    int wid  = threadIdx.x >> 6;
    int p    = blockIdx.x & 1;
    int bi   = blockIdx.x >> 1;
    int nblk = gridDim.x >> 1;

    const unsigned short* msl = msc + (size_t)p * (n + 1) * 64;
    int cbase = p * 64 + l8 * 8;

    for (int i = bi * 32 + wid * 8 + g; i < n; i += nblk * 32) {
        float a0, a1, a2, a3, a4, a5, a6, a7;
        {   // self loop init
            short8v v = *(const short8v*)&msl[(size_t)i * 64 + l8 * 8];
            a0 = bf2f((unsigned short)v[0]); a1 = bf2f((unsigned short)v[1]);
            a2 = bf2f((unsigned short)v[2]); a3 = bf2f((unsigned short)v[3]);
            a4 = bf2f((unsigned short)v[4]); a5 = bf2f((unsigned short)v[5]);
            a6 = bf2f((unsigned short)v[6]); a7 = bf2f((unsigned short)v[7]);
        }
        int deg = cnt[i]; deg = (deg < SLOTS) ? deg : SLOTS;
        int degR = (deg + 7) & ~7; degR = (degR < SLOTS) ? degR : SLOTS;
        const unsigned short* crow = col + (size_t)i * SLOTS;
        for (int base = 0; base < degR; base += 8) {
            short8v ci = *(const short8v*)&crow[base];
            #pragma unroll
            for (int u = 0; u < 8; ++u) {
                unsigned j = (unsigned short)ci[u];
                short8v v = *(const short8v*)&msl[(size_t)j * 64 + l8 * 8];
                a0 += bf2f((unsigned short)v[0]); a1 += bf2f((unsigned short)v[1]);
                a2 += bf2f((unsigned short)v[2]); a3 += bf2f((unsigned short)v[3]);
                a4 += bf2f((unsigned short)v[4]); a5 += bf2f((unsigned short)v[5]);
                a6 += bf2f((unsigned short)v[6]); a7 += bf2f((unsigned short)v[7]);
            }
        }
        if (WF32) {
            float di = dinv[i];
            float4 b0 = *(const float4*)&bias[cbase];
            float4 b1 = *(const float4*)&bias[cbase + 4];
            floatx4 r0 = {fmaf(di, a0, b0.x), fmaf(di, a1, b0.y),
                          fmaf(di, a2, b0.z), fmaf(di, a3, b0.w)};
            floatx4 r1 = {fmaf(di, a4, b1.x), fmaf(di, a5, b1.y),
                          fmaf(di, a6, b1.z), fmaf(di, a7, b1.w)};
            floatx4* o4 = (floatx4*)&out[(size_t)i * D + cbase];
            o4[0] = r0;
            o4[1] = r1;
        } else {
            short8v r;
            r[0] = (short)f2bf(a0); r[1] = (short)f2bf(a1);
            r[2] = (short)f2bf(a2); r[3] = (short)f2bf(a3);
            r[4] = (short)f2bf(a4); r[5] = (short)f2bf(a5);
            r[6] = (short)f2bf(a6); r[7] = (short)f2bf(a7);
            *(short8v*)&asl[((size_t)p * n + i) * 64 + l8 * 8] = r;
        }
    }
}

// ---------------- launch ----------------

static inline size_t align_up(size_t v, size_t a) { return (v + a - 1) & ~(a - 1); }

extern "C" void kernel_launch(void* const* d_in, const int* in_sizes, int n_in,
                              void* d_out, int out_size, void* d_ws, size_t ws_size,
                              hipStream_t stream) {
    const float* x  = (const float*)d_in[0];
    const int*   ei = (const int*)d_in[1];
    const float* W1 = (const float*)d_in[2];
    const float* b1 = (const float*)d_in[3];
    const float* W2 = (const float*)d_in[4];
    const float* b2 = (const float*)d_in[5];
    const float* W3 = (const float*)d_in[6];
    const float* b3 = (const float*)d_in[7];
    const float* g1  = (const float*)d_in[8];
    const float* be1 = (const float*)d_in[9];
    const float* g2  = (const float*)d_in[10];
    const float* be2 = (const float*)d_in[11];

    int N = in_sizes[0] / D;
    int E = in_sizes[1] / 2;
    const int* srcv = ei;
    const int* dstv = ei + E;

    float* out   = (float*)d_out;
    float* h2out = out;
    float* h3out = out + (size_t)N * D;

    char* w = (char*)d_ws;
    int* cnt = (int*)w;      w += align_up((size_t)N * 4, 256);
    float* dinv = (float*)w; w += align_up((size_t)N * 4, 256);
    unsigned short* wt = (unsigned short*)w;   w += align_up((size_t)3 * 2 * 16384 * 2, 256);
    unsigned short* colA = (unsigned short*)w; w += align_up((size_t)N * SLOTS * 2, 256);
    unsigned short* msc = (unsigned short*)w;  w += align_up((size_t)(N + 1) * D * 2, 256);
    unsigned short* asl = (unsigned short*)w;  w += align_up((size_t)N * D * 2, 256);

    wprep_kernel<<<192, 256, 0, stream>>>(W1, W2, W3, wt);
    hipMemsetAsync(cnt, 0, (size_t)N * sizeof(int), stream);
    zdum_kernel<<<1, 128, 0, stream>>>(msc, N);
    build_kernel<<<2048, 256, 0, stream>>>(srcv, dstv, cnt, colA, E, N);
    paddinv_kernel<<<(N + 255) / 256, 256, 0, stream>>>(cnt, colA, dinv, N, N);

    int gemmGrid = (N + 127) / 128;
    int aggGrid  = 2048;

    const unsigned short* wt1h = wt + 0 * 16384;
    const unsigned short* wt1l = wt + 1 * 16384;
    const unsigned short* wt2h = wt + 2 * 16384;
    const unsigned short* wt2l = wt + 3 * 16384;
    const unsigned short* wt3h = wt + 4 * 16384;
    const unsigned short* wt3l = wt + 5 * 16384;

    // layer 1: gemm(x) -> msc; agg -> asl (raw bf16 sums)
    gemm_kernel<0, false><<<gemmGrid, 256, 0, stream>>>(x, nullptr, wt1h, wt1l, dinv,
                                                        nullptr, nullptr, nullptr, nullptr, msc, N);
    agg_sl<false><<<aggGrid, 256, 0, stream>>>(msc, cnt, colA, dinv, b1, nullptr, asl, N);
    // layer 2: gemm(LN(asl1) fused) -> msc; agg -> asl
    gemm_kernel<2, false><<<gemmGrid, 256, 0, stream>>>(nullptr, asl, wt2h, wt2l, dinv,
                                                        b1, g1, be1, nullptr, msc, N);
    agg_sl<false><<<aggGrid, 256, 0, stream>>>(msc, cnt, colA, dinv, b2, nullptr, asl, N);
    // layer 3: gemm(LN(asl2) fused, emit h2) -> msc; agg -> h3 fp32
    gemm_kernel<2, true><<<gemmGrid, 256, 0, stream>>>(nullptr, asl, wt3h, wt3l, dinv,
                                                       b2, g2, be2, h2out, msc, N);
    agg_sl<true><<<aggGrid, 256, 0, stream>>>(msc, cnt, colA, dinv, b3, h3out, nullptr, N);
}

// Round 18
// 268.978 us; speedup vs baseline: 2.1431x; 1.0167x over previous
//
#include <hip/hip_runtime.h>
#include <hip/hip_bf16.h>

#define D 128
#define EPS 1e-5f
#define S1 32
#define S2 96
#define SLOTS 128

typedef __attribute__((ext_vector_type(8))) short short8v;
typedef __attribute__((ext_vector_type(4))) float floatx4;
typedef __attribute__((ext_vector_type(4))) int int4v;

__device__ __forceinline__ unsigned short f2bf(float f) {
    union { float f; unsigned u; } v; v.f = f;
    unsigned r = (v.u + 0x7FFF + ((v.u >> 16) & 1)) >> 16;
    return (unsigned short)r;
}
__device__ __forceinline__ float bf2f(unsigned short h) {
    union { unsigned u; float f; } v; v.u = ((unsigned)h) << 16;
    return v.f;
}

// ---------------- merged CSR build: split-slot table (col1 32/node, col2 96/node) ----

__global__ __launch_bounds__(256) void build_kernel(const int* __restrict__ src,
                                                    const int* __restrict__ dst,
                                                    int* __restrict__ cnt,
                                                    unsigned short* __restrict__ col1,
                                                    unsigned short* __restrict__ col2,
                                                    int E, int N) {
    int p   = blockIdx.x & 3;
    int lo  = (int)((long long)p * N / 4);
    int hi  = (int)((long long)(p + 1) * N / 4);
    int blk = blockIdx.x >> 2;
    int stride = (gridDim.x >> 2) * 256;
    int E4 = E >> 2;
    const int4v* dst4 = (const int4v*)dst;
    const int4v* src4 = (const int4v*)src;
    for (int e = blk * 256 + (int)threadIdx.x; e < E4; e += stride) {
        int4v d = __builtin_nontemporal_load(dst4 + e);
        int4v s = __builtin_nontemporal_load(src4 + e);
        #pragma unroll
        for (int u = 0; u < 4; ++u) {
            int dd = d[u];
            if (dd >= lo && dd < hi) {
                int pos = atomicAdd(&cnt[dd], 1);
                if (pos < S1) col1[(size_t)dd * S1 + pos] = (unsigned short)s[u];
                else if (pos < SLOTS) col2[(size_t)dd * S2 + (pos - S1)] = (unsigned short)s[u];
            }
        }
    }
    if (p == 0 && blk == 0 && threadIdx.x < (unsigned)(E & 3)) {
        int e = E4 * 4 + (int)threadIdx.x;
        int d = dst[e];
        int pos = atomicAdd(&cnt[d], 1);
        if (pos < S1) col1[(size_t)d * S1 + pos] = (unsigned short)src[e];
        else if (pos < SLOTS) col2[(size_t)d * S2 + (pos - S1)] = (unsigned short)src[e];
    }
}

// fused pad (to x8 with dummy index N) + dinv
__global__ __launch_bounds__(256) void paddinv_kernel(const int* __restrict__ cnt,
                                                      unsigned short* __restrict__ col1,
                                                      unsigned short* __restrict__ col2,
                                                      float* __restrict__ dinv,
                                                      int n, int N) {
    int i = blockIdx.x * 256 + threadIdx.x;
    if (i >= n) return;
    int deg0 = cnt[i];
    dinv[i] = rsqrtf((float)(deg0 + 1));
    int deg = (deg0 < SLOTS) ? deg0 : SLOTS;
    int end = (deg + 7) & ~7; end = (end < SLOTS) ? end : SLOTS;
    for (int s = deg; s < end; ++s) {
        if (s < S1) col1[(size_t)i * S1 + s] = (unsigned short)N;
        else        col2[(size_t)i * S2 + (s - S1)] = (unsigned short)N;
    }
}

// zero the dummy row N in both 64-col slices of msc
__global__ void zdum_kernel(unsigned short* __restrict__ msc, int n) {
    int t = threadIdx.x;   // 128 threads: slice t>>6, col t&63
    msc[((size_t)(t >> 6) * (n + 1) + n) * 64 + (t & 63)] = 0;
}

// ---------------- W precompute: transpose + bf16 hi/lo split ----------------

__global__ void wprep_kernel(const float* __restrict__ W1, const float* __restrict__ W2,
                             const float* __restrict__ W3, unsigned short* __restrict__ wt) {
    int gid = blockIdx.x * 256 + threadIdx.x;   // 0 .. 3*16384
    int z = gid >> 14;
    int r = gid & 16383;
    int c = r >> 7, k = r & 127;
    const float* W = (z == 0) ? W1 : ((z == 1) ? W2 : W3);
    float v = W[k * D + c];
    unsigned short hi = f2bf(v);
    unsigned short lo = f2bf(v - bf2f(hi));
    wt[(size_t)(z * 2 + 0) * 16384 + r] = hi;
    wt[(size_t)(z * 2 + 1) * 16384 + r] = lo;
}

// ---------------- MFMA GEMM -> sliced msc: msc[sl(2)][row][64], pre-scaled by dinv ----

__device__ __forceinline__ int sw_sidx(int row, int k) {   // short index, XOR-swizzled
    int byte = row * 256 + k * 2;
    byte ^= (row & 7) << 4;
    return byte >> 1;
}

template <int AMODE, bool WRITEH2>
__global__ __launch_bounds__(256, 2) void gemm_kernel(const float* __restrict__ A,
                                                      const unsigned short* __restrict__ aslin,
                                                      const unsigned short* __restrict__ wt_hi,
                                                      const unsigned short* __restrict__ wt_lo,
                                                      const float* __restrict__ dinv,
                                                      const float* __restrict__ bprev,
                                                      const float* __restrict__ gprev,
                                                      const float* __restrict__ beprev,
                                                      float* __restrict__ h2out,
                                                      unsigned short* __restrict__ msc, int n) {
    __shared__ short lds[2 * 16384];
    short* Ah = lds;
    short* Al = lds + 16384;

    const int t = threadIdx.x;
    const int rb = blockIdx.x * 128;
    const int lane = t & 63;

    #pragma unroll
    for (int p = 0; p < 8; ++p) {
        int chunk = p * 256 + t;
        int r = chunk >> 4, k0 = (chunk & 15) << 3;
        int row = rb + r;
        int rowc = (row < n) ? row : (n - 1);
        int si = sw_sidx(r, k0);
        if (AMODE == 0) {
            float4 f0 = *(const float4*)&A[(size_t)rowc * D + k0];
            float4 f1 = *(const float4*)&A[(size_t)rowc * D + k0 + 4];
            float fv[8] = {f0.x, f0.y, f0.z, f0.w, f1.x, f1.y, f1.z, f1.w};
            short8v hi, lo;
            #pragma unroll
            for (int j = 0; j < 8; ++j) {
                unsigned short h = f2bf(fv[j]);
                hi[j] = (short)h;
                lo[j] = (short)f2bf(fv[j] - bf2f(h));
            }
            *(short8v*)&Ah[si] = hi;
            *(short8v*)&Al[si] = lo;
        } else {
            short8v v = *(const short8v*)&aslin[((size_t)(k0 >> 6) * n + rowc) * 64 + (k0 & 63)];
            float di = dinv[rowc];
            float4 b0 = *(const float4*)&bprev[k0];
            float4 b1 = *(const float4*)&bprev[k0 + 4];
            float a[8];
            a[0] = fmaf(di, bf2f((unsigned short)v[0]), b0.x);
            a[1] = fmaf(di, bf2f((unsigned short)v[1]), b0.y);
            a[2] = fmaf(di, bf2f((unsigned short)v[2]), b0.z);
            a[3] = fmaf(di, bf2f((unsigned short)v[3]), b0.w);
            a[4] = fmaf(di, bf2f((unsigned short)v[4]), b1.x);
            a[5] = fmaf(di, bf2f((unsigned short)v[5]), b1.y);
            a[6] = fmaf(di, bf2f((unsigned short)v[6]), b1.z);
            a[7] = fmaf(di, bf2f((unsigned short)v[7]), b1.w);
            float s = 0.f, ss = 0.f;
            #pragma unroll
            for (int j = 0; j < 8; ++j) { s += a[j]; ss += a[j] * a[j]; }
            #pragma unroll
            for (int off = 1; off < 16; off <<= 1) {
                s  += __shfl_xor(s, off, 64);
                ss += __shfl_xor(ss, off, 64);
            }
            float mu   = s * (1.0f / D);
            float var  = ss * (1.0f / D) - mu * mu;
            float rstd = rsqrtf(var + EPS);
            float4 g0 = *(const float4*)&gprev[k0];
            float4 g1 = *(const float4*)&gprev[k0 + 4];
            float4 e0 = *(const float4*)&beprev[k0];
            float4 e1 = *(const float4*)&beprev[k0 + 4];
            float gv[8] = {g0.x, g0.y, g0.z, g0.w, g1.x, g1.y, g1.z, g1.w};
            float ev[8] = {e0.x, e0.y, e0.z, e0.w, e1.x, e1.y, e1.z, e1.w};
            #pragma unroll
            for (int j = 0; j < 8; ++j)
                a[j] = fmaxf((a[j] - mu) * rstd * gv[j] + ev[j], 0.f);
            if (WRITEH2 && row < n) {
                floatx4 r0 = {a[0], a[1], a[2], a[3]};
                floatx4 r1 = {a[4], a[5], a[6], a[7]};
                *(floatx4*)&h2out[(size_t)row * D + k0]     = r0;
                *(floatx4*)&h2out[(size_t)row * D + k0 + 4] = r1;
            }
            short8v hi, lo;
            #pragma unroll
            for (int j = 0; j < 8; ++j) {
                unsigned short h = f2bf(a[j]);
                hi[j] = (short)h;
                lo[j] = (short)f2bf(a[j] - bf2f(h));
            }
            *(short8v*)&Ah[si] = hi;
            *(short8v*)&Al[si] = lo;
        }
    }
    __syncthreads();

    const int wid  = t >> 6;
    const int wr = (wid & 1) * 64;
    const int wc = (wid >> 1) * 64;

    floatx4 acc[4][4];
    #pragma unroll
    for (int m = 0; m < 4; ++m)
        #pragma unroll
        for (int nn = 0; nn < 4; ++nn)
            acc[m][nn] = (floatx4){0.f, 0.f, 0.f, 0.f};

    #pragma unroll
    for (int ks = 0; ks < 4; ++ks) {
        const int kk = ks * 32 + (lane >> 4) * 8;
        short8v ah[4], al[4], bh[4], bl[4];
        #pragma unroll
        for (int nn = 0; nn < 4; ++nn) {   // W from global (L2)
            int c = wc + nn * 16 + (lane & 15);
            bh[nn] = *(const short8v*)&wt_hi[c * D + kk];
            bl[nn] = *(const short8v*)&wt_lo[c * D + kk];
        }
        #pragma unroll
        for (int m = 0; m < 4; ++m) {
            int si = sw_sidx(wr + m * 16 + (lane & 15), kk);
            ah[m] = *(const short8v*)&Ah[si];
            al[m] = *(const short8v*)&Al[si];
        }
        #pragma unroll
        for (int m = 0; m < 4; ++m)
            #pragma unroll
            for (int nn = 0; nn < 4; ++nn) {
                acc[m][nn] = __builtin_amdgcn_mfma_f32_16x16x32_bf16(ah[m], bh[nn], acc[m][nn], 0, 0, 0);
                acc[m][nn] = __builtin_amdgcn_mfma_f32_16x16x32_bf16(al[m], bh[nn], acc[m][nn], 0, 0, 0);
                acc[m][nn] = __builtin_amdgcn_mfma_f32_16x16x32_bf16(ah[m], bl[nn], acc[m][nn], 0, 0, 0);
            }
    }

    #pragma unroll
    for (int m = 0; m < 4; ++m) {
        #pragma unroll
        for (int j = 0; j < 4; ++j) {
            int row = rb + wr + m * 16 + (lane >> 4) * 4 + j;
            if (row < n) {
                float dv = dinv[row];
                #pragma unroll
                for (int nn = 0; nn < 4; ++nn) {
                    int colr = wc + nn * 16 + (lane & 15);
                    msc[((size_t)(colr >> 6) * (n + 1) + row) * 64 + (colr & 63)] =
                        f2bf(dv * acc[m][nn][j]);
                }
            }
        }
    }
}

// ---------------- feature-sliced aggregation, 2 slices x 64 cols, split col ----------

template <bool WF32>
__global__ __launch_bounds__(256) void agg_sl(const unsigned short* __restrict__ msc,
                                              const int* __restrict__ cnt,
                                              const unsigned short* __restrict__ col1,
                                              const unsigned short* __restrict__ col2,
                                              const float* __restrict__ dinv,
                                              const float* __restrict__ bias,
                                              float* __restrict__ out,
                                              unsigned short* __restrict__ asl, int n) {
    int lane = threadIdx.x & 63;
    int g    = lane >> 3;    // group 0..7 -> node
    int l8   = lane & 7;     // 8-col chunk within 64-col slice
    int wid  = threadIdx.x >> 6;
    int p    = blockIdx.x & 1;
    int bi   = blockIdx.x >> 1;
    int nblk = gridDim.x >> 1;

    const unsigned short* msl = msc + (size_t)p * (n + 1) * 64;
    int cbase = p * 64 + l8 * 8;

    for (int i = bi * 32 + wid * 8 + g; i < n; i += nblk * 32) {
        float a0, a1, a2, a3, a4, a5, a6, a7;
        {   // self loop init
            short8v v = *(const short8v*)&msl[(size_t)i * 64 + l8 * 8];
            a0 = bf2f((unsigned short)v[0]); a1 = bf2f((unsigned short)v[1]);
            a2 = bf2f((unsigned short)v[2]); a3 = bf2f((unsigned short)v[3]);
            a4 = bf2f((unsigned short)v[4]); a5 = bf2f((unsigned short)v[5]);
            a6 = bf2f((unsigned short)v[6]); a7 = bf2f((unsigned short)v[7]);
        }
        int deg = cnt[i]; deg = (deg < SLOTS) ? deg : SLOTS;
        int degR = (deg + 7) & ~7; degR = (degR < SLOTS) ? degR : SLOTS;
        const unsigned short* cr1 = col1 + (size_t)i * S1;
        const unsigned short* cr2 = col2 + (size_t)i * S2;
        for (int base = 0; base < degR; base += 8) {
            short8v ci = (base < S1) ? *(const short8v*)&cr1[base]
                                     : *(const short8v*)&cr2[base - S1];
            #pragma unroll
            for (int u = 0; u < 8; ++u) {
                unsigned j = (unsigned short)ci[u];
                short8v v = *(const short8v*)&msl[(size_t)j * 64 + l8 * 8];
                a0 += bf2f((unsigned short)v[0]); a1 += bf2f((unsigned short)v[1]);
                a2 += bf2f((unsigned short)v[2]); a3 += bf2f((unsigned short)v[3]);
                a4 += bf2f((unsigned short)v[4]); a5 += bf2f((unsigned short)v[5]);
                a6 += bf2f((unsigned short)v[6]); a7 += bf2f((unsigned short)v[7]);
            }
        }
        if (WF32) {
            float di = dinv[i];
            float4 b0 = *(const float4*)&bias[cbase];
            float4 b1 = *(const float4*)&bias[cbase + 4];
            floatx4 r0 = {fmaf(di, a0, b0.x), fmaf(di, a1, b0.y),
                          fmaf(di, a2, b0.z), fmaf(di, a3, b0.w)};
            floatx4 r1 = {fmaf(di, a4, b1.x), fmaf(di, a5, b1.y),
                          fmaf(di, a6, b1.z), fmaf(di, a7, b1.w)};
            floatx4* o4 = (floatx4*)&out[(size_t)i * D + cbase];
            o4[0] = r0;
            o4[1] = r1;
        } else {
            short8v r;
            r[0] = (short)f2bf(a0); r[1] = (short)f2bf(a1);
            r[2] = (short)f2bf(a2); r[3] = (short)f2bf(a3);
            r[4] = (short)f2bf(a4); r[5] = (short)f2bf(a5);
            r[6] = (short)f2bf(a6); r[7] = (short)f2bf(a7);
            *(short8v*)&asl[((size_t)p * n + i) * 64 + l8 * 8] = r;
        }
    }
}

// ---------------- launch ----------------

static inline size_t align_up(size_t v, size_t a) { return (v + a - 1) & ~(a - 1); }

extern "C" void kernel_launch(void* const* d_in, const int* in_sizes, int n_in,
                              void* d_out, int out_size, void* d_ws, size_t ws_size,
                              hipStream_t stream) {
    const float* x  = (const float*)d_in[0];
    const int*   ei = (const int*)d_in[1];
    const float* W1 = (const float*)d_in[2];
    const float* b1 = (const float*)d_in[3];
    const float* W2 = (const float*)d_in[4];
    const float* b2 = (const float*)d_in[5];
    const float* W3 = (const float*)d_in[6];
    const float* b3 = (const float*)d_in[7];
    const float* g1  = (const float*)d_in[8];
    const float* be1 = (const float*)d_in[9];
    const float* g2  = (const float*)d_in[10];
    const float* be2 = (const float*)d_in[11];

    int N = in_sizes[0] / D;
    int E = in_sizes[1] / 2;
    const int* srcv = ei;
    const int* dstv = ei + E;

    float* out   = (float*)d_out;
    float* h2out = out;
    float* h3out = out + (size_t)N * D;

    char* w = (char*)d_ws;
    int* cnt = (int*)w;      w += align_up((size_t)N * 4, 256);
    float* dinv = (float*)w; w += align_up((size_t)N * 4, 256);
    unsigned short* wt = (unsigned short*)w;    w += align_up((size_t)3 * 2 * 16384 * 2, 256);
    unsigned short* col1 = (unsigned short*)w;  w += align_up((size_t)N * S1 * 2, 256);
    unsigned short* col2 = (unsigned short*)w;  w += align_up((size_t)N * S2 * 2, 256);
    unsigned short* msc = (unsigned short*)w;   w += align_up((size_t)(N + 1) * D * 2, 256);
    unsigned short* asl = (unsigned short*)w;   w += align_up((size_t)N * D * 2, 256);

    wprep_kernel<<<192, 256, 0, stream>>>(W1, W2, W3, wt);
    hipMemsetAsync(cnt, 0, (size_t)N * sizeof(int), stream);
    zdum_kernel<<<1, 128, 0, stream>>>(msc, N);
    build_kernel<<<2048, 256, 0, stream>>>(srcv, dstv, cnt, col1, col2, E, N);
    paddinv_kernel<<<(N + 255) / 256, 256, 0, stream>>>(cnt, col1, col2, dinv, N, N);

    int gemmGrid = (N + 127) / 128;
    int aggGrid  = 2048;

    const unsigned short* wt1h = wt + 0 * 16384;
    const unsigned short* wt1l = wt + 1 * 16384;
    const unsigned short* wt2h = wt + 2 * 16384;
    const unsigned short* wt2l = wt + 3 * 16384;
    const unsigned short* wt3h = wt + 4 * 16384;
    const unsigned short* wt3l = wt + 5 * 16384;

    // layer 1
    gemm_kernel<0, false><<<gemmGrid, 256, 0, stream>>>(x, nullptr, wt1h, wt1l, dinv,
                                                        nullptr, nullptr, nullptr, nullptr, msc, N);
    agg_sl<false><<<aggGrid, 256, 0, stream>>>(msc, cnt, col1, col2, dinv, b1, nullptr, asl, N);
    // layer 2
    gemm_kernel<2, false><<<gemmGrid, 256, 0, stream>>>(nullptr, asl, wt2h, wt2l, dinv,
                                                        b1, g1, be1, nullptr, msc, N);
    agg_sl<false><<<aggGrid, 256, 0, stream>>>(msc, cnt, col1, col2, dinv, b2, nullptr, asl, N);
    // layer 3
    gemm_kernel<2, true><<<gemmGrid, 256, 0, stream>>>(nullptr, asl, wt3h, wt3l, dinv,
                                                       b2, g2, be2, h2out, msc, N);
    agg_sl<true><<<aggGrid, 256, 0, stream>>>(msc, cnt, col1, col2, dinv, b3, h3out, nullptr, N);
}

// Round 19
// 262.629 us; speedup vs baseline: 2.1949x; 1.0242x over previous
//
#include <hip/hip_runtime.h>
#include <hip/hip_bf16.h>

#define D 128
#define EPS 1e-5f
#define S1 32
#define S2 96
#define SLOTS 128

typedef __attribute__((ext_vector_type(8))) short short8v;
typedef __attribute__((ext_vector_type(4))) float floatx4;
typedef __attribute__((ext_vector_type(4))) int int4v;

__device__ __forceinline__ unsigned short f2bf(float f) {
    union { float f; unsigned u; } v; v.f = f;
    unsigned r = (v.u + 0x7FFF + ((v.u >> 16) & 1)) >> 16;
    return (unsigned short)r;
}
__device__ __forceinline__ float bf2f(unsigned short h) {
    union { unsigned u; float f; } v; v.u = ((unsigned)h) << 16;
    return v.f;
}

// ---------------- merged CSR build: split-slot table (col1 32/node, col2 96/node) ----

__global__ __launch_bounds__(256) void build_kernel(const int* __restrict__ src,
                                                    const int* __restrict__ dst,
                                                    int* __restrict__ cnt,
                                                    unsigned short* __restrict__ col1,
                                                    unsigned short* __restrict__ col2,
                                                    int E, int N) {
    int p   = blockIdx.x & 3;
    int lo  = (int)((long long)p * N / 4);
    int hi  = (int)((long long)(p + 1) * N / 4);
    int blk = blockIdx.x >> 2;
    int stride = (gridDim.x >> 2) * 256;
    int E4 = E >> 2;
    const int4v* dst4 = (const int4v*)dst;
    const int4v* src4 = (const int4v*)src;
    for (int e = blk * 256 + (int)threadIdx.x; e < E4; e += stride) {
        int4v d = __builtin_nontemporal_load(dst4 + e);
        int4v s = __builtin_nontemporal_load(src4 + e);
        #pragma unroll
        for (int u = 0; u < 4; ++u) {
            int dd = d[u];
            if (dd >= lo && dd < hi) {
                int pos = atomicAdd(&cnt[dd], 1);
                if (pos < S1) col1[(size_t)dd * S1 + pos] = (unsigned short)s[u];
                else if (pos < SLOTS) col2[(size_t)dd * S2 + (pos - S1)] = (unsigned short)s[u];
            }
        }
    }
    if (p == 0 && blk == 0 && threadIdx.x < (unsigned)(E & 3)) {
        int e = E4 * 4 + (int)threadIdx.x;
        int d = dst[e];
        int pos = atomicAdd(&cnt[d], 1);
        if (pos < S1) col1[(size_t)d * S1 + pos] = (unsigned short)src[e];
        else if (pos < SLOTS) col2[(size_t)d * S2 + (pos - S1)] = (unsigned short)src[e];
    }
}

// fused pad (to x8 with dummy index N) + dinv
__global__ __launch_bounds__(256) void paddinv_kernel(const int* __restrict__ cnt,
                                                      unsigned short* __restrict__ col1,
                                                      unsigned short* __restrict__ col2,
                                                      float* __restrict__ dinv,
                                                      int n, int N) {
    int i = blockIdx.x * 256 + threadIdx.x;
    if (i >= n) return;
    int deg0 = cnt[i];
    dinv[i] = rsqrtf((float)(deg0 + 1));
    int deg = (deg0 < SLOTS) ? deg0 : SLOTS;
    int end = (deg + 7) & ~7; end = (end < SLOTS) ? end : SLOTS;
    for (int s = deg; s < end; ++s) {
        if (s < S1) col1[(size_t)i * S1 + s] = (unsigned short)N;
        else        col2[(size_t)i * S2 + (s - S1)] = (unsigned short)N;
    }
}

// zero the dummy row N in both 64-col slices of msc
__global__ void zdum_kernel(unsigned short* __restrict__ msc, int n) {
    int t = threadIdx.x;   // 128 threads: slice t>>6, col t&63
    msc[((size_t)(t >> 6) * (n + 1) + n) * 64 + (t & 63)] = 0;
}

// ---------------- W precompute: transpose + bf16 hi/lo split ----------------

__global__ void wprep_kernel(const float* __restrict__ W1, const float* __restrict__ W2,
                             const float* __restrict__ W3, unsigned short* __restrict__ wt) {
    int gid = blockIdx.x * 256 + threadIdx.x;   // 0 .. 3*16384
    int z = gid >> 14;
    int r = gid & 16383;
    int c = r >> 7, k = r & 127;
    const float* W = (z == 0) ? W1 : ((z == 1) ? W2 : W3);
    float v = W[k * D + c];
    unsigned short hi = f2bf(v);
    unsigned short lo = f2bf(v - bf2f(hi));
    wt[(size_t)(z * 2 + 0) * 16384 + r] = hi;
    wt[(size_t)(z * 2 + 1) * 16384 + r] = lo;
}

// ---------------- MFMA GEMM -> sliced msc: msc[sl(2)][row][64], pre-scaled by dinv ----

__device__ __forceinline__ int sw_sidx(int row, int k) {   // short index, XOR-swizzled
    int byte = row * 256 + k * 2;
    byte ^= (row & 7) << 4;
    return byte >> 1;
}

// epilogue repack swizzle: wave-local 64x64 bf16 tile, byte = rl*128 + cl*2
__device__ __forceinline__ int ep_sidx(int rl, int cl) {
    int byte = rl * 128 + cl * 2;
    byte ^= (rl & 7) << 4;
    return byte >> 1;
}

template <int AMODE, bool WRITEH2>
__global__ __launch_bounds__(256, 2) void gemm_kernel(const float* __restrict__ A,
                                                      const unsigned short* __restrict__ aslin,
                                                      const unsigned short* __restrict__ wt_hi,
                                                      const unsigned short* __restrict__ wt_lo,
                                                      const float* __restrict__ dinv,
                                                      const float* __restrict__ bprev,
                                                      const float* __restrict__ gprev,
                                                      const float* __restrict__ beprev,
                                                      float* __restrict__ h2out,
                                                      unsigned short* __restrict__ msc, int n) {
    __shared__ short lds[2 * 16384];
    short* Ah = lds;
    short* Al = lds + 16384;

    const int t = threadIdx.x;
    const int rb = blockIdx.x * 128;
    const int lane = t & 63;

    #pragma unroll
    for (int p = 0; p < 8; ++p) {
        int chunk = p * 256 + t;
        int r = chunk >> 4, k0 = (chunk & 15) << 3;
        int row = rb + r;
        int rowc = (row < n) ? row : (n - 1);
        int si = sw_sidx(r, k0);
        if (AMODE == 0) {
            float4 f0 = *(const float4*)&A[(size_t)rowc * D + k0];
            float4 f1 = *(const float4*)&A[(size_t)rowc * D + k0 + 4];
            float fv[8] = {f0.x, f0.y, f0.z, f0.w, f1.x, f1.y, f1.z, f1.w};
            short8v hi, lo;
            #pragma unroll
            for (int j = 0; j < 8; ++j) {
                unsigned short h = f2bf(fv[j]);
                hi[j] = (short)h;
                lo[j] = (short)f2bf(fv[j] - bf2f(h));
            }
            *(short8v*)&Ah[si] = hi;
            *(short8v*)&Al[si] = lo;
        } else {
            short8v v = *(const short8v*)&aslin[((size_t)(k0 >> 6) * n + rowc) * 64 + (k0 & 63)];
            float di = dinv[rowc];
            float4 b0 = *(const float4*)&bprev[k0];
            float4 b1 = *(const float4*)&bprev[k0 + 4];
            float a[8];
            a[0] = fmaf(di, bf2f((unsigned short)v[0]), b0.x);
            a[1] = fmaf(di, bf2f((unsigned short)v[1]), b0.y);
            a[2] = fmaf(di, bf2f((unsigned short)v[2]), b0.z);
            a[3] = fmaf(di, bf2f((unsigned short)v[3]), b0.w);
            a[4] = fmaf(di, bf2f((unsigned short)v[4]), b1.x);
            a[5] = fmaf(di, bf2f((unsigned short)v[5]), b1.y);
            a[6] = fmaf(di, bf2f((unsigned short)v[6]), b1.z);
            a[7] = fmaf(di, bf2f((unsigned short)v[7]), b1.w);
            float s = 0.f, ss = 0.f;
            #pragma unroll
            for (int j = 0; j < 8; ++j) { s += a[j]; ss += a[j] * a[j]; }
            #pragma unroll
            for (int off = 1; off < 16; off <<= 1) {
                s  += __shfl_xor(s, off, 64);
                ss += __shfl_xor(ss, off, 64);
            }
            float mu   = s * (1.0f / D);
            float var  = ss * (1.0f / D) - mu * mu;
            float rstd = rsqrtf(var + EPS);
            float4 g0 = *(const float4*)&gprev[k0];
            float4 g1 = *(const float4*)&gprev[k0 + 4];
            float4 e0 = *(const float4*)&beprev[k0];
            float4 e1 = *(const float4*)&beprev[k0 + 4];
            float gv[8] = {g0.x, g0.y, g0.z, g0.w, g1.x, g1.y, g1.z, g1.w};
            float ev[8] = {e0.x, e0.y, e0.z, e0.w, e1.x, e1.y, e1.z, e1.w};
            #pragma unroll
            for (int j = 0; j < 8; ++j)
                a[j] = fmaxf((a[j] - mu) * rstd * gv[j] + ev[j], 0.f);
            if (WRITEH2 && row < n) {
                floatx4 r0 = {a[0], a[1], a[2], a[3]};
                floatx4 r1 = {a[4], a[5], a[6], a[7]};
                *(floatx4*)&h2out[(size_t)row * D + k0]     = r0;
                *(floatx4*)&h2out[(size_t)row * D + k0 + 4] = r1;
            }
            short8v hi, lo;
            #pragma unroll
            for (int j = 0; j < 8; ++j) {
                unsigned short h = f2bf(a[j]);
                hi[j] = (short)h;
                lo[j] = (short)f2bf(a[j] - bf2f(h));
            }
            *(short8v*)&Ah[si] = hi;
            *(short8v*)&Al[si] = lo;
        }
    }
    __syncthreads();

    const int wid  = t >> 6;
    const int wr = (wid & 1) * 64;
    const int wc = (wid >> 1) * 64;

    floatx4 acc[4][4];
    #pragma unroll
    for (int m = 0; m < 4; ++m)
        #pragma unroll
        for (int nn = 0; nn < 4; ++nn)
            acc[m][nn] = (floatx4){0.f, 0.f, 0.f, 0.f};

    #pragma unroll
    for (int ks = 0; ks < 4; ++ks) {
        const int kk = ks * 32 + (lane >> 4) * 8;
        short8v ah[4], al[4], bh[4], bl[4];
        #pragma unroll
        for (int nn = 0; nn < 4; ++nn) {   // W from global (L2)
            int c = wc + nn * 16 + (lane & 15);
            bh[nn] = *(const short8v*)&wt_hi[c * D + kk];
            bl[nn] = *(const short8v*)&wt_lo[c * D + kk];
        }
        #pragma unroll
        for (int m = 0; m < 4; ++m) {
            int si = sw_sidx(wr + m * 16 + (lane & 15), kk);
            ah[m] = *(const short8v*)&Ah[si];
            al[m] = *(const short8v*)&Al[si];
        }
        #pragma unroll
        for (int m = 0; m < 4; ++m)
            #pragma unroll
            for (int nn = 0; nn < 4; ++nn) {
                acc[m][nn] = __builtin_amdgcn_mfma_f32_16x16x32_bf16(ah[m], bh[nn], acc[m][nn], 0, 0, 0);
                acc[m][nn] = __builtin_amdgcn_mfma_f32_16x16x32_bf16(al[m], bh[nn], acc[m][nn], 0, 0, 0);
                acc[m][nn] = __builtin_amdgcn_mfma_f32_16x16x32_bf16(ah[m], bl[nn], acc[m][nn], 0, 0, 0);
            }
    }

    // ---- epilogue: repack wave's 64x64 tile via LDS, store coalesced dwordx4 ----
    __syncthreads();                      // A-tiles dead; reuse lds[0..16383]
    short* ep = lds + wid * 4096;         // 8KB per wave

    #pragma unroll
    for (int m = 0; m < 4; ++m) {
        int rbase = m * 16 + (lane >> 4) * 4;
        #pragma unroll
        for (int j = 0; j < 4; ++j) {
            int rl = rbase + j;
            int rowg = rb + wr + rl;
            int rowc = (rowg < n) ? rowg : (n - 1);
            float dv = dinv[rowc];
            #pragma unroll
            for (int nn = 0; nn < 4; ++nn) {
                int cl = nn * 16 + (lane & 15);
                ep[ep_sidx(rl, cl)] = (short)f2bf(dv * acc[m][nn][j]);
            }
        }
    }
    __builtin_amdgcn_s_waitcnt(0);        // drain LDS writes (same wave reads next)

    const size_t slbase = (size_t)(wc >> 6) * (n + 1) * 64;
    #pragma unroll
    for (int r8 = 0; r8 < 8; ++r8) {
        int rl = r8 * 8 + (lane >> 3);
        int cl0 = (lane & 7) * 8;
        short8v v = *(const short8v*)&ep[ep_sidx(rl, cl0)];
        int rowg = rb + wr + rl;
        if (rowg < n)
            *(short8v*)&msc[(slbase + (size_t)rowg * 64) + cl0] = v;
    }
}

// ---------------- feature-sliced aggregation, 2 slices x 64 cols, split col ----------

template <bool WF32>
__global__ __launch_bounds__(256) void agg_sl(const unsigned short* __restrict__ msc,
                                              const int* __restrict__ cnt,
                                              const unsigned short* __restrict__ col1,
                                              const unsigned short* __restrict__ col2,
                                              const float* __restrict__ dinv,
                                              const float* __restrict__ bias,
                                              float* __restrict__ out,
                                              unsigned short* __restrict__ asl, int n) {
    int lane = threadIdx.x & 63;
    int g    = lane >> 3;    // group 0..7 -> node
    int l8   = lane & 7;     // 8-col chunk within 64-col slice
    int wid  = threadIdx.x >> 6;
    int p    = blockIdx.x & 1;
    int bi   = blockIdx.x >> 1;
    int nblk = gridDim.x >> 1;

    const unsigned short* msl = msc + (size_t)p * (n + 1) * 64;
    int cbase = p * 64 + l8 * 8;

    for (int i = bi * 32 + wid * 8 + g; i < n; i += nblk * 32) {
        float a0, a1, a2, a3, a4, a5, a6, a7;
        {   // self loop init
            short8v v = *(const short8v*)&msl[(size_t)i * 64 + l8 * 8];
            a0 = bf2f((unsigned short)v[0]); a1 = bf2f((unsigned short)v[1]);
            a2 = bf2f((unsigned short)v[2]); a3 = bf2f((unsigned short)v[3]);
            a4 = bf2f((unsigned short)v[4]); a5 = bf2f((unsigned short)v[5]);
            a6 = bf2f((unsigned short)v[6]); a7 = bf2f((unsigned short)v[7]);
        }
        int deg = cnt[i]; deg = (deg < SLOTS) ? deg : SLOTS;
        int degR = (deg + 7) & ~7; degR = (degR < SLOTS) ? degR : SLOTS;
        const unsigned short* cr1 = col1 + (size_t)i * S1;
        const unsigned short* cr2 = col2 + (size_t)i * S2;
        for (int base = 0; base < degR; base += 8) {
            short8v ci = (base < S1) ? *(const short8v*)&cr1[base]
                                     : *(const short8v*)&cr2[base - S1];
            #pragma unroll
            for (int u = 0; u < 8; ++u) {
                unsigned j = (unsigned short)ci[u];
                short8v v = *(const short8v*)&msl[(size_t)j * 64 + l8 * 8];
                a0 += bf2f((unsigned short)v[0]); a1 += bf2f((unsigned short)v[1]);
                a2 += bf2f((unsigned short)v[2]); a3 += bf2f((unsigned short)v[3]);
                a4 += bf2f((unsigned short)v[4]); a5 += bf2f((unsigned short)v[5]);
                a6 += bf2f((unsigned short)v[6]); a7 += bf2f((unsigned short)v[7]);
            }
        }
        if (WF32) {
            float di = dinv[i];
            float4 b0 = *(const float4*)&bias[cbase];
            float4 b1 = *(const float4*)&bias[cbase + 4];
            floatx4 r0 = {fmaf(di, a0, b0.x), fmaf(di, a1, b0.y),
                          fmaf(di, a2, b0.z), fmaf(di, a3, b0.w)};
            floatx4 r1 = {fmaf(di, a4, b1.x), fmaf(di, a5, b1.y),
                          fmaf(di, a6, b1.z), fmaf(di, a7, b1.w)};
            floatx4* o4 = (floatx4*)&out[(size_t)i * D + cbase];
            o4[0] = r0;
            o4[1] = r1;
        } else {
            short8v r;
            r[0] = (short)f2bf(a0); r[1] = (short)f2bf(a1);
            r[2] = (short)f2bf(a2); r[3] = (short)f2bf(a3);
            r[4] = (short)f2bf(a4); r[5] = (short)f2bf(a5);
            r[6] = (short)f2bf(a6); r[7] = (short)f2bf(a7);
            *(short8v*)&asl[((size_t)p * n + i) * 64 + l8 * 8] = r;
        }
    }
}

// ---------------- launch ----------------

static inline size_t align_up(size_t v, size_t a) { return (v + a - 1) & ~(a - 1); }

extern "C" void kernel_launch(void* const* d_in, const int* in_sizes, int n_in,
                              void* d_out, int out_size, void* d_ws, size_t ws_size,
                              hipStream_t stream) {
    const float* x  = (const float*)d_in[0];
    const int*   ei = (const int*)d_in[1];
    const float* W1 = (const float*)d_in[2];
    const float* b1 = (const float*)d_in[3];
    const float* W2 = (const float*)d_in[4];
    const float* b2 = (const float*)d_in[5];
    const float* W3 = (const float*)d_in[6];
    const float* b3 = (const float*)d_in[7];
    const float* g1  = (const float*)d_in[8];
    const float* be1 = (const float*)d_in[9];
    const float* g2  = (const float*)d_in[10];
    const float* be2 = (const float*)d_in[11];

    int N = in_sizes[0] / D;
    int E = in_sizes[1] / 2;
    const int* srcv = ei;
    const int* dstv = ei + E;

    float* out   = (float*)d_out;
    float* h2out = out;
    float* h3out = out + (size_t)N * D;

    char* w = (char*)d_ws;
    int* cnt = (int*)w;      w += align_up((size_t)N * 4, 256);
    float* dinv = (float*)w; w += align_up((size_t)N * 4, 256);
    unsigned short* wt = (unsigned short*)w;    w += align_up((size_t)3 * 2 * 16384 * 2, 256);
    unsigned short* col1 = (unsigned short*)w;  w += align_up((size_t)N * S1 * 2, 256);
    unsigned short* col2 = (unsigned short*)w;  w += align_up((size_t)N * S2 * 2, 256);
    unsigned short* msc = (unsigned short*)w;   w += align_up((size_t)(N + 1) * D * 2, 256);
    unsigned short* asl = (unsigned short*)w;   w += align_up((size_t)N * D * 2, 256);

    wprep_kernel<<<192, 256, 0, stream>>>(W1, W2, W3, wt);
    hipMemsetAsync(cnt, 0, (size_t)N * sizeof(int), stream);
    zdum_kernel<<<1, 128, 0, stream>>>(msc, N);
    build_kernel<<<2048, 256, 0, stream>>>(srcv, dstv, cnt, col1, col2, E, N);
    paddinv_kernel<<<(N + 255) / 256, 256, 0, stream>>>(cnt, col1, col2, dinv, N, N);

    int gemmGrid = (N + 127) / 128;
    int aggGrid  = 2048;

    const unsigned short* wt1h = wt + 0 * 16384;
    const unsigned short* wt1l = wt + 1 * 16384;
    const unsigned short* wt2h = wt + 2 * 16384;
    const unsigned short* wt2l = wt + 3 * 16384;
    const unsigned short* wt3h = wt + 4 * 16384;
    const unsigned short* wt3l = wt + 5 * 16384;

    // layer 1
    gemm_kernel<0, false><<<gemmGrid, 256, 0, stream>>>(x, nullptr, wt1h, wt1l, dinv,
                                                        nullptr, nullptr, nullptr, nullptr, msc, N);
    agg_sl<false><<<aggGrid, 256, 0, stream>>>(msc, cnt, col1, col2, dinv, b1, nullptr, asl, N);
    // layer 2
    gemm_kernel<2, false><<<gemmGrid, 256, 0, stream>>>(nullptr, asl, wt2h, wt2l, dinv,
                                                        b1, g1, be1, nullptr, msc, N);
    agg_sl<false><<<aggGrid, 256, 0, stream>>>(msc, cnt, col1, col2, dinv, b2, nullptr, asl, N);
    // layer 3
    gemm_kernel<2, true><<<gemmGrid, 256, 0, stream>>>(nullptr, asl, wt3h, wt3l, dinv,
                                                       b2, g2, be2, h2out, msc, N);
    agg_sl<true><<<aggGrid, 256, 0, stream>>>(msc, cnt, col1, col2, dinv, b3, h3out, nullptr, N);
}